// Round 1
// baseline (723.435 us; speedup 1.0000x reference)
//
#include <hip/hip_runtime.h>
#include <hip/hip_bf16.h>

#define NQ_   8192
#define DM_   256
#define NH_   6
#define DH_   64
#define BATCH 2

// ---------------- workspace layout (bytes) ----------------
// v (bf16): levels concat, [b][h][pix][d]
//   L0: 2*6*7680*64 = 5,898,240 el ; L1: 1,474,560 ; L2: 368,640  -> 7,741,440 bf16 = 15,482,880 B
// qraw (f32): 16384 x 486 = 31,850,496 B  @ 15,482,880
// mid  (f32): 16384 x 384 = 25,165,824 B  @ 47,333,376
static const size_t VOFF_L0 = 0;
static const size_t VOFF_L1 = 5898240;
static const size_t VOFF_L2 = 7372800;
static const size_t QRAW_BYTE_OFF = 15482880;
static const size_t MID_BYTE_OFF  = 47333376;

// ============ Kernel A: value projection  C[p,n] = sum_c feat[c,p] * Wv[c,n] + bv ============
// feat: (B, DM, HW) ; Wv: (DM, 384) ; out: bf16 v[b][h][pix][d]
__global__ __launch_bounds__(256) void value_gemm(const float* __restrict__ feat,
                                                  const float* __restrict__ Wv,
                                                  const float* __restrict__ bv,
                                                  __hip_bfloat16* __restrict__ vout,
                                                  int HW) {
    __shared__ float As[32][64];
    __shared__ float Bs[32][128];
    const int tid = threadIdx.x;
    const int p0 = blockIdx.x * 64;
    const int n0 = blockIdx.y * 128;
    const int b  = blockIdx.z;
    float acc[4][8];
#pragma unroll
    for (int i = 0; i < 4; ++i)
#pragma unroll
        for (int j = 0; j < 8; ++j) acc[i][j] = 0.f;
    const int tm = (tid & 15) * 4;
    const int tn = (tid >> 4) * 8;

    for (int k0 = 0; k0 < DM_; k0 += 32) {
#pragma unroll
        for (int it = 0; it < 2; ++it) {
            int idx = tid + it * 256;          // 0..511
            int c = idx >> 4;
            int p4 = (idx & 15) * 4;
            int p = p0 + p4;
            float4 v = make_float4(0.f, 0.f, 0.f, 0.f);
            if (p < HW) v = *(const float4*)&feat[((size_t)b * DM_ + k0 + c) * HW + p];
            *(float4*)&As[c][p4] = v;
        }
#pragma unroll
        for (int it = 0; it < 4; ++it) {
            int idx = tid + it * 256;          // 0..1023
            int c = idx >> 5;
            int n4 = (idx & 31) * 4;
            *(float4*)&Bs[c][n4] = *(const float4*)&Wv[(size_t)(k0 + c) * 384 + n0 + n4];
        }
        __syncthreads();
#pragma unroll
        for (int c = 0; c < 32; ++c) {
            float4 a  = *(const float4*)&As[c][tm];
            float4 b0 = *(const float4*)&Bs[c][tn];
            float4 b1 = *(const float4*)&Bs[c][tn + 4];
            float av[4] = {a.x, a.y, a.z, a.w};
            float bb[8] = {b0.x, b0.y, b0.z, b0.w, b1.x, b1.y, b1.z, b1.w};
#pragma unroll
            for (int i = 0; i < 4; ++i)
#pragma unroll
                for (int j = 0; j < 8; ++j) acc[i][j] += av[i] * bb[j];
        }
        __syncthreads();
    }
#pragma unroll
    for (int i = 0; i < 4; ++i) {
        int p = p0 + tm + i;
        if (p >= HW) continue;
#pragma unroll
        for (int j = 0; j < 8; ++j) {
            int n = n0 + tn + j;
            float val = acc[i][j] + bv[n];
            int h = n >> 6, d = n & 63;
            vout[((size_t)(b * NH_ + h) * HW + p) * DH_ + d] = __float2bfloat16(val);
        }
    }
}

// ============ Kernel B: query projection  qraw[m, n] = (x+pe)[m,:] @ [W_off | W_attn] + bias ============
__global__ __launch_bounds__(256) void query_gemm(const float* __restrict__ x,
                                                  const float* __restrict__ pe,
                                                  const float* __restrict__ Woff,
                                                  const float* __restrict__ boff,
                                                  const float* __restrict__ Wattn,
                                                  const float* __restrict__ battn,
                                                  float* __restrict__ qraw) {
    __shared__ float As[32][68];   // +4 pad, keeps 16B alignment
    __shared__ float Bs[32][128];
    const int tid = threadIdx.x;
    const int m0 = blockIdx.x * 64;
    const int n0 = blockIdx.y * 128;
    float acc[4][8];
#pragma unroll
    for (int i = 0; i < 4; ++i)
#pragma unroll
        for (int j = 0; j < 8; ++j) acc[i][j] = 0.f;
    const int tm = (tid & 15) * 4;
    const int tn = (tid >> 4) * 8;

    for (int k0 = 0; k0 < DM_; k0 += 32) {
        {
            int i = tid >> 2;
#pragma unroll
            for (int r = 0; r < 2; ++r) {
                int quad = (tid & 3) + r * 4;
                int c = quad * 4;
                size_t off = (size_t)(m0 + i) * DM_ + k0 + c;
                float4 xv = *(const float4*)&x[off];
                float4 pv = *(const float4*)&pe[off];
                As[c + 0][i] = xv.x + pv.x;
                As[c + 1][i] = xv.y + pv.y;
                As[c + 2][i] = xv.z + pv.z;
                As[c + 3][i] = xv.w + pv.w;
            }
        }
#pragma unroll
        for (int it = 0; it < 16; ++it) {
            int idx = tid + it * 256;          // 0..4095
            int n = idx & 127;
            int c = idx >> 7;
            int ng = n0 + n;
            float v = 0.f;
            if (ng < 324)      v = Woff[(size_t)(k0 + c) * 324 + ng];
            else if (ng < 486) v = Wattn[(size_t)(k0 + c) * 162 + (ng - 324)];
            Bs[c][n] = v;
        }
        __syncthreads();
#pragma unroll
        for (int c = 0; c < 32; ++c) {
            float4 a  = *(const float4*)&As[c][tm];
            float4 b0 = *(const float4*)&Bs[c][tn];
            float4 b1 = *(const float4*)&Bs[c][tn + 4];
            float av[4] = {a.x, a.y, a.z, a.w};
            float bb[8] = {b0.x, b0.y, b0.z, b0.w, b1.x, b1.y, b1.z, b1.w};
#pragma unroll
            for (int i = 0; i < 4; ++i)
#pragma unroll
                for (int j = 0; j < 8; ++j) acc[i][j] += av[i] * bb[j];
        }
        __syncthreads();
    }
#pragma unroll
    for (int i = 0; i < 4; ++i) {
        int m = m0 + tm + i;
#pragma unroll
        for (int j = 0; j < 8; ++j) {
            int ng = n0 + tn + j;
            if (ng < 486) {
                float bias = (ng < 324) ? boff[ng] : battn[ng - 324];
                qraw[(size_t)m * 486 + ng] = acc[i][j] + bias;
            }
        }
    }
}

// ============ Kernel D: fused softmax + projection + bilinear sampling ============
// one block = one (b,q); 384 threads = 6 waves, wave h handles head h, lane = channel d
__global__ __launch_bounds__(384) void sample_kernel(const float* __restrict__ qraw,
                                                     const float* __restrict__ coor,
                                                     const float* __restrict__ cam2img,
                                                     const float* __restrict__ l2c,
                                                     const __hip_bfloat16* __restrict__ vws,
                                                     float* __restrict__ mid) {
    __shared__ float s_w[162][4];
    __shared__ int   s_idx[162][4];
    __shared__ float s_logit[6][27];
    __shared__ float s_m[6], s_is[6];
    const int tid = threadIdx.x;
    const int bq = blockIdx.x;           // b*NQ + q
    const int b = bq >> 13;              // NQ = 8192

    if (tid < 162) {
        int h = tid / 27, j = tid - h * 27;
        s_logit[h][j] = qraw[(size_t)bq * 486 + 324 + h * 27 + j];
    }
    __syncthreads();
    if (tid < 6) {
        float m = -1e30f;
#pragma unroll
        for (int j = 0; j < 27; ++j) m = fmaxf(m, s_logit[tid][j]);
        float s = 0.f;
#pragma unroll
        for (int j = 0; j < 27; ++j) s += expf(s_logit[tid][j] - m);
        s_m[tid] = m;
        s_is[tid] = 1.f / s;
    }
    __syncthreads();
    if (tid < 162) {
        int h = tid / 27, j = tid - h * 27;
        int l = j / 9;
        const int WLs[3] = {160, 80, 40};
        const int HLs[3] = {48, 24, 12};
        int wl = WLs[l], hl = HLs[l];
        float attn = expf(s_logit[h][j] - s_m[h]) * s_is[h];
        // projection to uv
        float c0 = coor[(size_t)bq * 3 + 0];
        float c1 = coor[(size_t)bq * 3 + 1];
        float c2 = coor[(size_t)bq * 3 + 2];
        const float* L = l2c + b * 16;
        const float* C = cam2img + b * 16;
        float pc0 = L[0] * c0 + L[1] * c1 + L[2]  * c2 + L[3];
        float pc1 = L[4] * c0 + L[5] * c1 + L[6]  * c2 + L[7];
        float pc2 = L[8] * c0 + L[9] * c1 + L[10] * c2 + L[11];
        float q0 = C[0] * pc0 + C[1] * pc1 + C[2]  * pc2 + C[3];
        float q1 = C[4] * pc0 + C[5] * pc1 + C[6]  * pc2 + C[7];
        float q2 = C[8] * pc0 + C[9] * pc1 + C[10] * pc2 + C[11];
        float u = q0 / q2, v = q1 / q2;
        float refx = u * ((float)wl * (1.f / 1280.f));
        float refy = v * ((float)hl * (1.f / 384.f));
        float ox = qraw[(size_t)bq * 486 + h * 54 + j * 2];
        float oy = qraw[(size_t)bq * 486 + h * 54 + j * 2 + 1];
        float X = refx + ox - 0.5f;
        float Y = refy + oy - 0.5f;
        float x0f = floorf(X), y0f = floorf(Y);
        float fx = X - x0f, fy = Y - y0f;
        int ix = (int)x0f, iy = (int)y0f;
        int cx0 = min(max(ix, 0), wl - 1), cx1 = min(max(ix + 1, 0), wl - 1);
        int cy0 = min(max(iy, 0), hl - 1), cy1 = min(max(iy + 1, 0), hl - 1);
        bool vx0 = (ix >= 0) && (ix < wl);
        bool vx1 = (ix + 1 >= 0) && (ix + 1 < wl);
        bool vy0 = (iy >= 0) && (iy < hl);
        bool vy1 = (iy + 1 >= 0) && (iy + 1 < hl);
        s_idx[tid][0] = cy0 * wl + cx0;
        s_idx[tid][1] = cy0 * wl + cx1;
        s_idx[tid][2] = cy1 * wl + cx0;
        s_idx[tid][3] = cy1 * wl + cx1;
        s_w[tid][0] = (vx0 && vy0) ? attn * (1.f - fx) * (1.f - fy) : 0.f;
        s_w[tid][1] = (vx1 && vy0) ? attn * fx * (1.f - fy) : 0.f;
        s_w[tid][2] = (vx0 && vy1) ? attn * (1.f - fx) * fy : 0.f;
        s_w[tid][3] = (vx1 && vy1) ? attn * fx * fy : 0.f;
    }
    __syncthreads();

    const int h = tid >> 6;              // 0..5
    const int d = tid & 63;
    float acc = 0.f;
    const size_t LOFF[3] = {VOFF_L0, VOFF_L1, VOFF_L2};
    const int HWs[3] = {7680, 1920, 480};
#pragma unroll
    for (int l = 0; l < 3; ++l) {
        const __hip_bfloat16* vb = vws + LOFF[l] + (size_t)(b * NH_ + h) * HWs[l] * DH_;
#pragma unroll
        for (int p = 0; p < 9; ++p) {
            int j = l * 9 + p;
            int4  id = *(const int4*)s_idx[h * 27 + j];
            float4 w = *(const float4*)s_w[h * 27 + j];
            acc += w.x * __bfloat162float(vb[(size_t)id.x * DH_ + d]);
            acc += w.y * __bfloat162float(vb[(size_t)id.y * DH_ + d]);
            acc += w.z * __bfloat162float(vb[(size_t)id.z * DH_ + d]);
            acc += w.w * __bfloat162float(vb[(size_t)id.w * DH_ + d]);
        }
    }
    mid[(size_t)bq * 384 + h * 64 + d] = acc;
}

// ============ Kernel E: output projection  out = mid @ W_out + b_out ============
__global__ __launch_bounds__(256) void out_gemm(const float* __restrict__ mid,
                                                const float* __restrict__ Wout,
                                                const float* __restrict__ bout,
                                                float* __restrict__ out) {
    __shared__ float As[32][68];
    __shared__ float Bs[32][128];
    const int tid = threadIdx.x;
    const int m0 = blockIdx.x * 64;
    const int n0 = blockIdx.y * 128;
    float acc[4][8];
#pragma unroll
    for (int i = 0; i < 4; ++i)
#pragma unroll
        for (int j = 0; j < 8; ++j) acc[i][j] = 0.f;
    const int tm = (tid & 15) * 4;
    const int tn = (tid >> 4) * 8;

    for (int k0 = 0; k0 < 384; k0 += 32) {
        {
            int i = tid >> 2;
#pragma unroll
            for (int r = 0; r < 2; ++r) {
                int quad = (tid & 3) + r * 4;
                int c = quad * 4;
                float4 xv = *(const float4*)&mid[(size_t)(m0 + i) * 384 + k0 + c];
                As[c + 0][i] = xv.x;
                As[c + 1][i] = xv.y;
                As[c + 2][i] = xv.z;
                As[c + 3][i] = xv.w;
            }
        }
#pragma unroll
        for (int it = 0; it < 4; ++it) {
            int idx = tid + it * 256;
            int c = idx >> 5;
            int n4 = (idx & 31) * 4;
            *(float4*)&Bs[c][n4] = *(const float4*)&Wout[(size_t)(k0 + c) * 256 + n0 + n4];
        }
        __syncthreads();
#pragma unroll
        for (int c = 0; c < 32; ++c) {
            float4 a  = *(const float4*)&As[c][tm];
            float4 b0 = *(const float4*)&Bs[c][tn];
            float4 b1 = *(const float4*)&Bs[c][tn + 4];
            float av[4] = {a.x, a.y, a.z, a.w};
            float bb[8] = {b0.x, b0.y, b0.z, b0.w, b1.x, b1.y, b1.z, b1.w};
#pragma unroll
            for (int i = 0; i < 4; ++i)
#pragma unroll
                for (int j = 0; j < 8; ++j) acc[i][j] += av[i] * bb[j];
        }
        __syncthreads();
    }
#pragma unroll
    for (int i = 0; i < 4; ++i) {
        int m = m0 + tm + i;
#pragma unroll
        for (int j = 0; j < 8; ++j) {
            int n = n0 + tn + j;
            out[(size_t)m * 256 + n] = acc[i][j] + bout[n];
        }
    }
}

extern "C" void kernel_launch(void* const* d_in, const int* in_sizes, int n_in,
                              void* d_out, int out_size, void* d_ws, size_t ws_size,
                              hipStream_t stream) {
    const float* x      = (const float*)d_in[0];
    const float* pe     = (const float*)d_in[1];
    const float* coor   = (const float*)d_in[2];
    const float* c2i    = (const float*)d_in[3];
    const float* l2c    = (const float*)d_in[4];
    const float* feat0  = (const float*)d_in[5];
    const float* feat1  = (const float*)d_in[6];
    const float* feat2  = (const float*)d_in[7];
    const float* Wv     = (const float*)d_in[8];
    const float* bv     = (const float*)d_in[9];
    const float* Woff   = (const float*)d_in[10];
    const float* boff   = (const float*)d_in[11];
    const float* Wattn  = (const float*)d_in[12];
    const float* battn  = (const float*)d_in[13];
    const float* Wout   = (const float*)d_in[14];
    const float* bout   = (const float*)d_in[15];

    __hip_bfloat16* vws = (__hip_bfloat16*)d_ws;
    float* qraw = (float*)((char*)d_ws + QRAW_BYTE_OFF);
    float* mid  = (float*)((char*)d_ws + MID_BYTE_OFF);
    float* out  = (float*)d_out;

    // value projection per level
    value_gemm<<<dim3(120, 3, BATCH), 256, 0, stream>>>(feat0, Wv, bv, vws + VOFF_L0, 7680);
    value_gemm<<<dim3(30,  3, BATCH), 256, 0, stream>>>(feat1, Wv, bv, vws + VOFF_L1, 1920);
    value_gemm<<<dim3(8,   3, BATCH), 256, 0, stream>>>(feat2, Wv, bv, vws + VOFF_L2, 480);
    // query projection (off + attn logits)
    query_gemm<<<dim3(256, 4), 256, 0, stream>>>(x, pe, Woff, boff, Wattn, battn, qraw);
    // fused softmax + uv projection + bilinear sampling
    sample_kernel<<<dim3(BATCH * NQ_), 384, 0, stream>>>(qraw, coor, c2i, l2c, vws, mid);
    // output projection
    out_gemm<<<dim3(256, 2), 256, 0, stream>>>(mid, Wout, bout, out);
}

// Round 2
// 328.751 us; speedup vs baseline: 2.2006x; 2.2006x over previous
//
#include <hip/hip_runtime.h>
#include <hip/hip_bf16.h>

#define NQ_   8192
#define DM_   256
#define NH_   6
#define DH_   64
#define BATCH 2

typedef __attribute__((ext_vector_type(8))) short short8;
typedef __attribute__((ext_vector_type(4))) float float4v;

// ---------------- workspace layout ----------------
// v bf16 [b][h][p][d], levels concat        @ 0          (15,482,880 B)
// qraw f32 [16384][486]                     @ 15,482,880 (31,850,496 B)
// mid  bf16 [16384][384]                    @ 47,333,376 (12,582,912 B)
// wT   bf16 (WvT|WoffT|WattnT|WoutT rows)   @ 59,916,288 (   642,048 B)
// featT bf16 [b][p][c] per level concat     @ 60,558,336 (10,321,920 B)
static const size_t VOFF_L0 = 0;
static const size_t VOFF_L1 = 5898240;
static const size_t VOFF_L2 = 7372800;
static const size_t QRAW_BYTE_OFF  = 15482880;
static const size_t MID_BYTE_OFF   = 47333376;
static const size_t WT_BYTE_OFF    = 59916288;
static const size_t FEATT_BYTE_OFF = 60558336;
// wT element offsets
static const size_t WVT_OFF   = 0;        // 384 rows x 256
static const size_t WOFFT_OFF = 98304;    // 324 rows x 256
static const size_t WATTNT_OFF= 181248;   // 162 rows x 256
static const size_t WOUTT_OFF = 222720;   // 256 rows x 384
// featT element offsets
static const size_t FT_L0 = 0;
static const size_t FT_L1 = 3932160;
static const size_t FT_L2 = 4915200;

__device__ __forceinline__ unsigned short f2bf(float f) {
    unsigned int u = __float_as_uint(f);
    unsigned int r = (u + 0x7fffu + ((u >> 16) & 1u)) >> 16;
    return (unsigned short)r;
}

// ============ prep: transpose+convert all weight matrices to bf16 [n][k] ============
__global__ __launch_bounds__(256) void prep_w(const float* __restrict__ Wv,
                                              const float* __restrict__ Woff,
                                              const float* __restrict__ Wattn,
                                              const float* __restrict__ Wout,
                                              unsigned short* __restrict__ wT) {
    int r = blockIdx.x, t = threadIdx.x;
    const float* src; int N, n, K; size_t doff;
    if (r < 384)      { src = Wv;    N = 384; n = r;       K = 256; doff = (size_t)r * 256; }
    else if (r < 708) { src = Woff;  N = 324; n = r - 384; K = 256; doff = (size_t)r * 256; }
    else if (r < 870) { src = Wattn; N = 162; n = r - 708; K = 256; doff = (size_t)r * 256; }
    else              { src = Wout;  N = 256; n = r - 870; K = 384; doff = WOUTT_OFF + (size_t)(r - 870) * 384; }
    for (int k = t; k < K; k += 256) wT[doff + k] = f2bf(src[(size_t)k * N + n]);
}

// ============ prep: feat [b][c][p] f32 -> featT [b][p][c] bf16 ============
__global__ __launch_bounds__(1024) void prep_feat(const float* __restrict__ src,
                                                  unsigned short* __restrict__ dst,
                                                  int HW) {
    __shared__ float tile[32][33];
    int tx = threadIdx.x, ty = threadIdx.y;
    int p0 = blockIdx.x * 32, c0 = blockIdx.y * 32, b = blockIdx.z;
    tile[ty][tx] = src[((size_t)(b * DM_ + c0 + ty)) * HW + p0 + tx];
    __syncthreads();
    dst[((size_t)b * HW + p0 + ty) * DM_ + c0 + tx] = f2bf(tile[tx][ty]);
}

// ============ shared MFMA inner block: 128x128 tile, 4 waves 2x2, 4x4 frags ============
__device__ __forceinline__ void mfma_block(const short A[][40], const short B[][40],
                                           int wm, int wn, int lane, float4v acc[4][4]) {
    int m_base = wm + (lane & 15);
    int n_base = wn + (lane & 15);
    int q8 = (lane >> 4) * 8;
    short8 af[4], bf[4];
#pragma unroll
    for (int i = 0; i < 4; ++i) af[i] = *(const short8*)&A[m_base + i * 16][q8];
#pragma unroll
    for (int j = 0; j < 4; ++j) bf[j] = *(const short8*)&B[n_base + j * 16][q8];
#pragma unroll
    for (int i = 0; i < 4; ++i)
#pragma unroll
        for (int j = 0; j < 4; ++j)
            acc[i][j] = __builtin_amdgcn_mfma_f32_16x16x32_bf16(af[i], bf[j], acc[i][j], 0, 0, 0);
}

// ============ value GEMM: C[p, n] = featT[p,:] @ WvT[n,:]^T + bv ============
__global__ __launch_bounds__(256) void value_gemm(const unsigned short* __restrict__ fT,
                                                  const unsigned short* __restrict__ wvT,
                                                  const float* __restrict__ bv,
                                                  unsigned short* __restrict__ vout,
                                                  int HW) {
    __shared__ short A[128][40];
    __shared__ short B[128][40];
    const int tid = threadIdx.x;
    const int p0 = blockIdx.x * 128, n0 = blockIdx.y * 128, b = blockIdx.z;
    const int lane = tid & 63, wave = tid >> 6;
    const int wm = (wave & 1) * 64, wn = (wave >> 1) * 64;
    const unsigned short* Asrc = fT + (size_t)b * HW * DM_;
    float4v acc[4][4];
#pragma unroll
    for (int i = 0; i < 4; ++i)
#pragma unroll
        for (int j = 0; j < 4; ++j) acc[i][j] = (float4v){0.f, 0.f, 0.f, 0.f};

    for (int k0 = 0; k0 < DM_; k0 += 32) {
#pragma unroll
        for (int it = 0; it < 2; ++it) {
            int idx = tid + it * 256;
            int r = idx >> 2, sg = idx & 3;
            int p = p0 + r; if (p >= HW) p = HW - 1;
            *(short8*)&A[r][sg * 8] = *(const short8*)&Asrc[(size_t)p * DM_ + k0 + sg * 8];
            *(short8*)&B[r][sg * 8] = *(const short8*)&wvT[(size_t)(n0 + r) * DM_ + k0 + sg * 8];
        }
        __syncthreads();
        mfma_block(A, B, wm, wn, lane, acc);
        __syncthreads();
    }
    int colb = n0 + wn + (lane & 15);
    int rowq = (lane >> 4) * 4;
#pragma unroll
    for (int i = 0; i < 4; ++i)
#pragma unroll
        for (int j = 0; j < 4; ++j) {
            int n = colb + j * 16;
            int h = n >> 6, d = n & 63;
            float bias = bv[n];
#pragma unroll
            for (int r = 0; r < 4; ++r) {
                int p = p0 + wm + i * 16 + rowq + r;
                if (p < HW)
                    vout[((size_t)(b * NH_ + h) * HW + p) * DH_ + d] = f2bf(acc[i][j][r] + bias);
            }
        }
}

// ============ query GEMM: qraw[m, n] = (x+pe)[m,:] @ [Woff|Wattn] + bias ============
__global__ __launch_bounds__(256) void query_gemm(const float* __restrict__ x,
                                                  const float* __restrict__ pe,
                                                  const unsigned short* __restrict__ wqT,
                                                  const float* __restrict__ boff,
                                                  const float* __restrict__ battn,
                                                  float* __restrict__ qraw) {
    __shared__ short A[128][40];
    __shared__ short B[128][40];
    const int tid = threadIdx.x;
    const int m0 = blockIdx.x * 128, n0 = blockIdx.y * 128;
    const int lane = tid & 63, wave = tid >> 6;
    const int wm = (wave & 1) * 64, wn = (wave >> 1) * 64;
    float4v acc[4][4];
#pragma unroll
    for (int i = 0; i < 4; ++i)
#pragma unroll
        for (int j = 0; j < 4; ++j) acc[i][j] = (float4v){0.f, 0.f, 0.f, 0.f};

    for (int k0 = 0; k0 < DM_; k0 += 32) {
#pragma unroll
        for (int it = 0; it < 2; ++it) {
            int idx = tid + it * 256;
            int r = idx >> 2, sg = idx & 3;
            const float* xr = x  + (size_t)(m0 + r) * DM_ + k0 + sg * 8;
            const float* pr = pe + (size_t)(m0 + r) * DM_ + k0 + sg * 8;
            float4 xa = *(const float4*)xr, xb = *(const float4*)(xr + 4);
            float4 pa = *(const float4*)pr, pb = *(const float4*)(pr + 4);
            short8 v;
            v[0] = (short)f2bf(xa.x + pa.x); v[1] = (short)f2bf(xa.y + pa.y);
            v[2] = (short)f2bf(xa.z + pa.z); v[3] = (short)f2bf(xa.w + pa.w);
            v[4] = (short)f2bf(xb.x + pb.x); v[5] = (short)f2bf(xb.y + pb.y);
            v[6] = (short)f2bf(xb.z + pb.z); v[7] = (short)f2bf(xb.w + pb.w);
            *(short8*)&A[r][sg * 8] = v;
            int g = n0 + r;
            short8 bz = (short8)0;
            if (g < 486) bz = *(const short8*)&wqT[WOFFT_OFF + (size_t)g * DM_ + k0 + sg * 8];
            *(short8*)&B[r][sg * 8] = bz;
        }
        __syncthreads();
        mfma_block(A, B, wm, wn, lane, acc);
        __syncthreads();
    }
    int colb = n0 + wn + (lane & 15);
    int rowq = (lane >> 4) * 4;
#pragma unroll
    for (int i = 0; i < 4; ++i)
#pragma unroll
        for (int j = 0; j < 4; ++j) {
            int n = colb + j * 16;
            if (n < 486) {
                float bias = (n < 324) ? boff[n] : battn[n - 324];
#pragma unroll
                for (int r = 0; r < 4; ++r) {
                    int m = m0 + wm + i * 16 + rowq + r;
                    qraw[(size_t)m * 486 + n] = acc[i][j][r] + bias;
                }
            }
        }
}

// ============ out GEMM: out[m, n] = mid[m,:] @ WoutT[n,:]^T + bout ============
__global__ __launch_bounds__(256) void out_gemm(const unsigned short* __restrict__ mid,
                                                const unsigned short* __restrict__ woT,
                                                const float* __restrict__ bout,
                                                float* __restrict__ out) {
    __shared__ short A[128][40];
    __shared__ short B[128][40];
    const int tid = threadIdx.x;
    const int m0 = blockIdx.x * 128, n0 = blockIdx.y * 128;
    const int lane = tid & 63, wave = tid >> 6;
    const int wm = (wave & 1) * 64, wn = (wave >> 1) * 64;
    float4v acc[4][4];
#pragma unroll
    for (int i = 0; i < 4; ++i)
#pragma unroll
        for (int j = 0; j < 4; ++j) acc[i][j] = (float4v){0.f, 0.f, 0.f, 0.f};

    for (int k0 = 0; k0 < 384; k0 += 32) {
#pragma unroll
        for (int it = 0; it < 2; ++it) {
            int idx = tid + it * 256;
            int r = idx >> 2, sg = idx & 3;
            *(short8*)&A[r][sg * 8] = *(const short8*)&mid[(size_t)(m0 + r) * 384 + k0 + sg * 8];
            *(short8*)&B[r][sg * 8] = *(const short8*)&woT[(size_t)(n0 + r) * 384 + k0 + sg * 8];
        }
        __syncthreads();
        mfma_block(A, B, wm, wn, lane, acc);
        __syncthreads();
    }
    int colb = n0 + wn + (lane & 15);
    int rowq = (lane >> 4) * 4;
#pragma unroll
    for (int i = 0; i < 4; ++i)
#pragma unroll
        for (int j = 0; j < 4; ++j) {
            int n = colb + j * 16;
            float bias = bout[n];
#pragma unroll
            for (int r = 0; r < 4; ++r) {
                int m = m0 + wm + i * 16 + rowq + r;
                out[(size_t)m * 256 + n] = acc[i][j][r] + bias;
            }
        }
}

// ============ fused softmax + projection + paired bilinear sampling ============
// one block = one (b,q); 6 waves, wave h = head h; lane&31 = channel pair, lane>>5 = x-slot
__global__ __launch_bounds__(384) void sample_kernel(const float* __restrict__ qraw,
                                                     const float* __restrict__ coor,
                                                     const float* __restrict__ cam2img,
                                                     const float* __restrict__ l2c,
                                                     const unsigned short* __restrict__ vws,
                                                     unsigned short* __restrict__ mid) {
    __shared__ float s_w[162][4];
    __shared__ int   s_idx[162][2];
    __shared__ float s_logit[6][27];
    __shared__ float s_m[6], s_is[6];
    const int tid = threadIdx.x;
    const int bq = blockIdx.x;
    const int b = bq >> 13;

    if (tid < 162) {
        int h = tid / 27, j = tid - h * 27;
        s_logit[h][j] = qraw[(size_t)bq * 486 + 324 + h * 27 + j];
    }
    __syncthreads();
    if (tid < 6) {
        float m = -1e30f;
#pragma unroll
        for (int j = 0; j < 27; ++j) m = fmaxf(m, s_logit[tid][j]);
        float s = 0.f;
#pragma unroll
        for (int j = 0; j < 27; ++j) s += expf(s_logit[tid][j] - m);
        s_m[tid] = m;
        s_is[tid] = 1.f / s;
    }
    __syncthreads();
    if (tid < 162) {
        int h = tid / 27, j = tid - h * 27;
        int l = j / 9;
        const int WLs[3] = {160, 80, 40};
        const int HLs[3] = {48, 24, 12};
        int wl = WLs[l], hl = HLs[l];
        float attn = expf(s_logit[h][j] - s_m[h]) * s_is[h];
        float c0 = coor[(size_t)bq * 3 + 0];
        float c1 = coor[(size_t)bq * 3 + 1];
        float c2 = coor[(size_t)bq * 3 + 2];
        const float* L = l2c + b * 16;
        const float* C = cam2img + b * 16;
        float pc0 = L[0] * c0 + L[1] * c1 + L[2]  * c2 + L[3];
        float pc1 = L[4] * c0 + L[5] * c1 + L[6]  * c2 + L[7];
        float pc2 = L[8] * c0 + L[9] * c1 + L[10] * c2 + L[11];
        float q0 = C[0] * pc0 + C[1] * pc1 + C[2]  * pc2 + C[3];
        float q1 = C[4] * pc0 + C[5] * pc1 + C[6]  * pc2 + C[7];
        float q2 = C[8] * pc0 + C[9] * pc1 + C[10] * pc2 + C[11];
        float u = q0 / q2, v = q1 / q2;
        float refx = u * ((float)wl * (1.f / 1280.f));
        float refy = v * ((float)hl * (1.f / 384.f));
        float ox = qraw[(size_t)bq * 486 + h * 54 + j * 2];
        float oy = qraw[(size_t)bq * 486 + h * 54 + j * 2 + 1];
        float X = refx + ox - 0.5f;
        float Y = refy + oy - 0.5f;
        float x0f = floorf(X), y0f = floorf(Y);
        float fx = X - x0f, fy = Y - y0f;
        int ix = (int)x0f, iy = (int)y0f;
        // paired x-slots: base bx covers pixels bx, bx+1 (always in-bounds)
        int bx = min(max(ix, 0), wl - 2);
        float wx0 = ((bx == ix) ? (1.f - fx) : 0.f) + ((bx == ix + 1) ? fx : 0.f);
        float wx1 = ((bx + 1 == ix) ? (1.f - fx) : 0.f) + ((bx + 1 == ix + 1) ? fx : 0.f);
        int cy0 = min(max(iy, 0), hl - 1);
        int cy1 = min(max(iy + 1, 0), hl - 1);
        float wy0 = (iy >= 0 && iy < hl) ? (1.f - fy) : 0.f;
        float wy1 = (iy + 1 >= 0 && iy + 1 < hl) ? fy : 0.f;
        s_idx[tid][0] = cy0 * wl + bx;
        s_idx[tid][1] = cy1 * wl + bx;
        s_w[tid][0] = attn * wy0 * wx0;
        s_w[tid][1] = attn * wy0 * wx1;
        s_w[tid][2] = attn * wy1 * wx0;
        s_w[tid][3] = attn * wy1 * wx1;
    }
    __syncthreads();

    const int h = tid >> 6;
    const int lane = tid & 63;
    const int s = lane >> 5;
    float accx = 0.f, accy = 0.f;
    const size_t LOFF[3] = {VOFF_L0, VOFF_L1, VOFF_L2};
    const int HWs[3] = {7680, 1920, 480};
#pragma unroll
    for (int l = 0; l < 3; ++l) {
        const unsigned short* vb = vws + LOFF[l] + (size_t)(b * NH_ + h) * HWs[l] * DH_;
#pragma unroll
        for (int p = 0; p < 9; ++p) {
            int jj = h * 27 + l * 9 + p;
            int2   id = *(const int2*)s_idx[jj];
            float4 w  = *(const float4*)s_w[jj];
            float w0 = s ? w.y : w.x;
            float w1 = s ? w.w : w.z;
            unsigned v0 = *(const unsigned*)&vb[(size_t)id.x * DH_ + 2 * lane];
            unsigned v1 = *(const unsigned*)&vb[(size_t)id.y * DH_ + 2 * lane];
            accx += w0 * __uint_as_float(v0 << 16);
            accy += w0 * __uint_as_float(v0 & 0xffff0000u);
            accx += w1 * __uint_as_float(v1 << 16);
            accy += w1 * __uint_as_float(v1 & 0xffff0000u);
        }
    }
    accx += __shfl_xor(accx, 32, 64);
    accy += __shfl_xor(accy, 32, 64);
    if (lane < 32) {
        unsigned pack = (unsigned)f2bf(accx) | ((unsigned)f2bf(accy) << 16);
        *(unsigned*)&mid[(size_t)bq * 384 + h * DH_ + 2 * lane] = pack;
    }
}

extern "C" void kernel_launch(void* const* d_in, const int* in_sizes, int n_in,
                              void* d_out, int out_size, void* d_ws, size_t ws_size,
                              hipStream_t stream) {
    const float* x      = (const float*)d_in[0];
    const float* pe     = (const float*)d_in[1];
    const float* coor   = (const float*)d_in[2];
    const float* c2i    = (const float*)d_in[3];
    const float* l2c    = (const float*)d_in[4];
    const float* feat0  = (const float*)d_in[5];
    const float* feat1  = (const float*)d_in[6];
    const float* feat2  = (const float*)d_in[7];
    const float* Wv     = (const float*)d_in[8];
    const float* bv     = (const float*)d_in[9];
    const float* Woff   = (const float*)d_in[10];
    const float* boff   = (const float*)d_in[11];
    const float* Wattn  = (const float*)d_in[12];
    const float* battn  = (const float*)d_in[13];
    const float* Wout   = (const float*)d_in[14];
    const float* bout   = (const float*)d_in[15];

    unsigned short* vws = (unsigned short*)d_ws;
    float* qraw         = (float*)((char*)d_ws + QRAW_BYTE_OFF);
    unsigned short* mid = (unsigned short*)((char*)d_ws + MID_BYTE_OFF);
    unsigned short* wT  = (unsigned short*)((char*)d_ws + WT_BYTE_OFF);
    unsigned short* fT  = (unsigned short*)((char*)d_ws + FEATT_BYTE_OFF);
    float* out          = (float*)d_out;

    prep_w<<<dim3(1126), 256, 0, stream>>>(Wv, Woff, Wattn, Wout, wT);
    prep_feat<<<dim3(240, 8, BATCH), dim3(32, 32), 0, stream>>>(feat0, fT + FT_L0, 7680);
    prep_feat<<<dim3(60,  8, BATCH), dim3(32, 32), 0, stream>>>(feat1, fT + FT_L1, 1920);
    prep_feat<<<dim3(15,  8, BATCH), dim3(32, 32), 0, stream>>>(feat2, fT + FT_L2, 480);

    value_gemm<<<dim3(60, 3, BATCH), 256, 0, stream>>>(fT + FT_L0, wT + WVT_OFF, bv, vws + VOFF_L0, 7680);
    value_gemm<<<dim3(15, 3, BATCH), 256, 0, stream>>>(fT + FT_L1, wT + WVT_OFF, bv, vws + VOFF_L1, 1920);
    value_gemm<<<dim3(4,  3, BATCH), 256, 0, stream>>>(fT + FT_L2, wT + WVT_OFF, bv, vws + VOFF_L2, 480);

    query_gemm<<<dim3(128, 4), 256, 0, stream>>>(x, pe, wT, boff, battn, qraw);

    sample_kernel<<<dim3(BATCH * NQ_), 384, 0, stream>>>(qraw, coor, c2i, l2c, vws, mid);

    out_gemm<<<dim3(128, 2), 256, 0, stream>>>(mid, wT + WOUTT_OFF, bout, out);
}

// Round 3
// 258.405 us; speedup vs baseline: 2.7996x; 1.2722x over previous
//
#include <hip/hip_runtime.h>
#include <hip/hip_bf16.h>

#define NQ_   8192
#define DM_   256
#define NH_   6
#define DH_   64
#define BATCH 2

typedef __attribute__((ext_vector_type(8))) short short8;
typedef __attribute__((ext_vector_type(4))) float float4v;

// ---------------- workspace layout ----------------
static const size_t VOFF_L0 = 0;
static const size_t VOFF_L1 = 5898240;
static const size_t VOFF_L2 = 7372800;
static const size_t QRAW_BYTE_OFF  = 15482880;
static const size_t MID_BYTE_OFF   = 47333376;
static const size_t WT_BYTE_OFF    = 59916288;
static const size_t FEATT_BYTE_OFF = 60558336;
// wT element offsets
static const size_t WVT_OFF   = 0;        // 384 rows x 256
static const size_t WOFFT_OFF = 98304;    // 324 rows x 256
static const size_t WATTNT_OFF= 181248;   // 162 rows x 256
static const size_t WOUTT_OFF = 222720;   // 256 rows x 384
// featT element offsets
static const size_t FT_L0 = 0;
static const size_t FT_L1 = 3932160;
static const size_t FT_L2 = 4915200;

__device__ __forceinline__ unsigned short f2bf(float f) {
    unsigned int u = __float_as_uint(f);
    unsigned int r = (u + 0x7fffu + ((u >> 16) & 1u)) >> 16;
    return (unsigned short)r;
}

// ============ prep_all: weights transpose (blocks 0..1125) + feat transpose (rest) ============
__global__ __launch_bounds__(256) void prep_all(const float* __restrict__ Wv,
                                                const float* __restrict__ Woff,
                                                const float* __restrict__ Wattn,
                                                const float* __restrict__ Wout,
                                                const float* __restrict__ feat0,
                                                const float* __restrict__ feat1,
                                                const float* __restrict__ feat2,
                                                unsigned short* __restrict__ wT,
                                                unsigned short* __restrict__ fT) {
    const int pid = blockIdx.x, t = threadIdx.x;
    if (pid < 1126) {
        int r = pid;
        const float* src; int N, n, K; size_t doff;
        if (r < 384)      { src = Wv;    N = 384; n = r;       K = 256; doff = (size_t)r * 256; }
        else if (r < 708) { src = Woff;  N = 324; n = r - 384; K = 256; doff = (size_t)r * 256; }
        else if (r < 870) { src = Wattn; N = 162; n = r - 708; K = 256; doff = (size_t)r * 256; }
        else              { src = Wout;  N = 256; n = r - 870; K = 384; doff = WOUTT_OFF + (size_t)(r - 870) * 384; }
        for (int k = t; k < K; k += 256) wT[doff + k] = f2bf(src[(size_t)k * N + n]);
        return;
    }
    __shared__ float tile[32][33];
    int f = pid - 1126;
    const float* src; unsigned short* dst; int HW;
    if (f < 3840)      { src = feat0; dst = fT + FT_L0; HW = 7680; }
    else if (f < 4800) { src = feat1; dst = fT + FT_L1; HW = 1920; f -= 3840; }
    else               { src = feat2; dst = fT + FT_L2; HW = 480;  f -= 4800; }
    int pb = f >> 4, rem = f & 15, cb = rem >> 1, b = rem & 1;
    int p0 = pb * 32, c0 = cb * 32;
    int tx = t & 31, ty = t >> 5;
#pragma unroll
    for (int i = 0; i < 4; ++i) {
        int c = c0 + ty + i * 8;
        tile[ty + i * 8][tx] = src[((size_t)(b * DM_ + c)) * HW + p0 + tx];
    }
    __syncthreads();
#pragma unroll
    for (int i = 0; i < 4; ++i) {
        int p = p0 + ty + i * 8;
        dst[((size_t)b * HW + p) * DM_ + c0 + tx] = f2bf(tile[tx][ty + i * 8]);
    }
}

// ============ shared MFMA inner block: 128x128 tile, 4 waves 2x2, 4x4 frags ============
__device__ __forceinline__ void mfma_block(const short A[][40], const short B[][40],
                                           int wm, int wn, int lane, float4v acc[4][4]) {
    int m_base = wm + (lane & 15);
    int n_base = wn + (lane & 15);
    int q8 = (lane >> 4) * 8;
    short8 af[4], bf[4];
#pragma unroll
    for (int i = 0; i < 4; ++i) af[i] = *(const short8*)&A[m_base + i * 16][q8];
#pragma unroll
    for (int j = 0; j < 4; ++j) bf[j] = *(const short8*)&B[n_base + j * 16][q8];
#pragma unroll
    for (int i = 0; i < 4; ++i)
#pragma unroll
        for (int j = 0; j < 4; ++j)
            acc[i][j] = __builtin_amdgcn_mfma_f32_16x16x32_bf16(af[i], bf[j], acc[i][j], 0, 0, 0);
}

// ============ fused value GEMM (blocks 0..473) + query GEMM (blocks 474..985) ============
__global__ __launch_bounds__(256) void gemm_vq(const unsigned short* __restrict__ fT,
                                               const unsigned short* __restrict__ wT,
                                               const float* __restrict__ bv,
                                               unsigned short* __restrict__ vws,
                                               const float* __restrict__ x,
                                               const float* __restrict__ pe,
                                               const float* __restrict__ boff,
                                               const float* __restrict__ battn,
                                               float* __restrict__ qraw) {
    __shared__ short A[128][40];
    __shared__ short B[128][40];
    const int tid = threadIdx.x;
    const int lane = tid & 63, wave = tid >> 6;
    const int wm = (wave & 1) * 64, wn = (wave >> 1) * 64;
    const int id = blockIdx.x;
    float4v acc[4][4];
#pragma unroll
    for (int i = 0; i < 4; ++i)
#pragma unroll
        for (int j = 0; j < 4; ++j) acc[i][j] = (float4v){0.f, 0.f, 0.f, 0.f};

    if (id < 474) {
        // ---- value path ----
        int pb = id / 6, rem = id % 6;
        int nb = rem >> 1, b = rem & 1;
        int pbl, HW; size_t ftoff, voff;
        if (pb < 60)      { pbl = pb;      HW = 7680; ftoff = FT_L0; voff = VOFF_L0; }
        else if (pb < 75) { pbl = pb - 60; HW = 1920; ftoff = FT_L1; voff = VOFF_L1; }
        else              { pbl = pb - 75; HW = 480;  ftoff = FT_L2; voff = VOFF_L2; }
        const int p0 = pbl * 128, n0 = nb * 128;
        const unsigned short* Asrc = fT + ftoff + (size_t)b * HW * DM_;
        const unsigned short* wvT = wT + WVT_OFF;

        for (int k0 = 0; k0 < DM_; k0 += 32) {
#pragma unroll
            for (int it = 0; it < 2; ++it) {
                int idx = tid + it * 256;
                int r = idx >> 2, sg = idx & 3;
                int p = p0 + r; if (p >= HW) p = HW - 1;
                *(short8*)&A[r][sg * 8] = *(const short8*)&Asrc[(size_t)p * DM_ + k0 + sg * 8];
                *(short8*)&B[r][sg * 8] = *(const short8*)&wvT[(size_t)(n0 + r) * DM_ + k0 + sg * 8];
            }
            __syncthreads();
            mfma_block(A, B, wm, wn, lane, acc);
            __syncthreads();
        }
        int colb = n0 + wn + (lane & 15);
        int rowq = (lane >> 4) * 4;
#pragma unroll
        for (int i = 0; i < 4; ++i)
#pragma unroll
            for (int j = 0; j < 4; ++j) {
                int n = colb + j * 16;
                int h = n >> 6, d = n & 63;
                float bias = bv[n];
#pragma unroll
                for (int r = 0; r < 4; ++r) {
                    int p = p0 + wm + i * 16 + rowq + r;
                    if (p < HW)
                        vws[voff + ((size_t)(b * NH_ + h) * HW + p) * DH_ + d] = f2bf(acc[i][j][r] + bias);
                }
            }
    } else {
        // ---- query path ----
        int qid = id - 474;
        const int m0 = (qid & 127) * 128, n0 = (qid >> 7) * 128;
        for (int k0 = 0; k0 < DM_; k0 += 32) {
#pragma unroll
            for (int it = 0; it < 2; ++it) {
                int idx = tid + it * 256;
                int r = idx >> 2, sg = idx & 3;
                const float* xr = x  + (size_t)(m0 + r) * DM_ + k0 + sg * 8;
                const float* pr = pe + (size_t)(m0 + r) * DM_ + k0 + sg * 8;
                float4 xa = *(const float4*)xr, xb = *(const float4*)(xr + 4);
                float4 pa = *(const float4*)pr, pb = *(const float4*)(pr + 4);
                short8 v;
                v[0] = (short)f2bf(xa.x + pa.x); v[1] = (short)f2bf(xa.y + pa.y);
                v[2] = (short)f2bf(xa.z + pa.z); v[3] = (short)f2bf(xa.w + pa.w);
                v[4] = (short)f2bf(xb.x + pb.x); v[5] = (short)f2bf(xb.y + pb.y);
                v[6] = (short)f2bf(xb.z + pb.z); v[7] = (short)f2bf(xb.w + pb.w);
                *(short8*)&A[r][sg * 8] = v;
                int g = n0 + r;
                short8 bz = (short8)0;
                if (g < 486) bz = *(const short8*)&wT[WOFFT_OFF + (size_t)g * DM_ + k0 + sg * 8];
                *(short8*)&B[r][sg * 8] = bz;
            }
            __syncthreads();
            mfma_block(A, B, wm, wn, lane, acc);
            __syncthreads();
        }
        int colb = n0 + wn + (lane & 15);
        int rowq = (lane >> 4) * 4;
#pragma unroll
        for (int i = 0; i < 4; ++i)
#pragma unroll
            for (int j = 0; j < 4; ++j) {
                int n = colb + j * 16;
                if (n < 486) {
                    float bias = (n < 324) ? boff[n] : battn[n - 324];
#pragma unroll
                    for (int r = 0; r < 4; ++r) {
                        int m = m0 + wm + i * 16 + rowq + r;
                        qraw[(size_t)m * 486 + n] = acc[i][j][r] + bias;
                    }
                }
            }
    }
}

// ============ fused softmax + projection + scalarized bilinear gather ============
// 6 waves; gather: wave h = head h, lane&31 = channel pair, lane>>5 = x-slot
__global__ __launch_bounds__(384) void sample_kernel(const float* __restrict__ qraw,
                                                     const float* __restrict__ coor,
                                                     const float* __restrict__ cam2img,
                                                     const float* __restrict__ l2c,
                                                     const unsigned short* __restrict__ vws,
                                                     unsigned short* __restrict__ mid) {
    __shared__ float s_w[162][2][2];   // [tap][x-slot][y]
    __shared__ int   s_off[162][2];    // [tap][y] pre-scaled byte offsets
    const int tid = threadIdx.x;
    const int bq = blockIdx.x;
    const int b = bq >> 13;

    if (tid < 192) {
        int h = tid >> 5, j = tid & 31;
        bool act = j < 27;
        float logit = act ? qraw[(size_t)bq * 486 + 324 + h * 27 + j] : -1e30f;
        // half-wave (32-lane) softmax
        float m = logit;
#pragma unroll
        for (int msk = 16; msk >= 1; msk >>= 1) m = fmaxf(m, __shfl_xor(m, msk, 32));
        float e = act ? __expf(logit - m) : 0.f;
        float ssum = e;
#pragma unroll
        for (int msk = 16; msk >= 1; msk >>= 1) ssum += __shfl_xor(ssum, msk, 32);
        if (act) {
            float attn = e * __frcp_rn(ssum);
            int l = (j >= 18) ? 2 : ((j >= 9) ? 1 : 0);
            int wl = 160 >> l, hl = 48 >> l;
            float sc = (l == 0) ? 0.125f : ((l == 1) ? 0.0625f : 0.03125f);
            float c0 = coor[(size_t)bq * 3 + 0];
            float c1 = coor[(size_t)bq * 3 + 1];
            float c2 = coor[(size_t)bq * 3 + 2];
            const float* L = l2c + b * 16;
            const float* C = cam2img + b * 16;
            float pc0 = L[0] * c0 + L[1] * c1 + L[2]  * c2 + L[3];
            float pc1 = L[4] * c0 + L[5] * c1 + L[6]  * c2 + L[7];
            float pc2 = L[8] * c0 + L[9] * c1 + L[10] * c2 + L[11];
            float q0 = C[0] * pc0 + C[1] * pc1 + C[2]  * pc2 + C[3];
            float q1 = C[4] * pc0 + C[5] * pc1 + C[6]  * pc2 + C[7];
            float q2 = C[8] * pc0 + C[9] * pc1 + C[10] * pc2 + C[11];
            float u = q0 / q2, v = q1 / q2;
            float refx = u * sc, refy = v * sc;
            float ox = qraw[(size_t)bq * 486 + h * 54 + j * 2];
            float oy = qraw[(size_t)bq * 486 + h * 54 + j * 2 + 1];
            float X = refx + ox - 0.5f;
            float Y = refy + oy - 0.5f;
            float x0f = floorf(X), y0f = floorf(Y);
            float fx = X - x0f, fy = Y - y0f;
            int ix = (int)x0f, iy = (int)y0f;
            int bx = min(max(ix, 0), wl - 2);
            float wx0 = ((bx == ix) ? (1.f - fx) : 0.f) + ((bx == ix + 1) ? fx : 0.f);
            float wx1 = ((bx + 1 == ix) ? (1.f - fx) : 0.f) + ((bx + 1 == ix + 1) ? fx : 0.f);
            int cy0 = min(max(iy, 0), hl - 1);
            int cy1 = min(max(iy + 1, 0), hl - 1);
            float wy0 = (iy >= 0 && iy < hl) ? (1.f - fy) : 0.f;
            float wy1 = (iy + 1 >= 0 && iy + 1 < hl) ? fy : 0.f;
            int jj = h * 27 + j;
            s_off[jj][0] = (cy0 * wl + bx) * 128;
            s_off[jj][1] = (cy1 * wl + bx) * 128;
            s_w[jj][0][0] = attn * wy0 * wx0;
            s_w[jj][0][1] = attn * wy1 * wx0;
            s_w[jj][1][0] = attn * wy0 * wx1;
            s_w[jj][1][1] = attn * wy1 * wx1;
        }
    }
    __syncthreads();

    const int h = __builtin_amdgcn_readfirstlane(tid >> 6);
    const int lane = tid & 63;
    const int s = lane >> 5;
    const int lane4 = lane * 4;
    const char* vbytes = (const char*)vws;
    const char* vbs[3] = {
        vbytes + 2 * VOFF_L0 + (size_t)(b * NH_ + h) * 7680 * 128,
        vbytes + 2 * VOFF_L1 + (size_t)(b * NH_ + h) * 1920 * 128,
        vbytes + 2 * VOFF_L2 + (size_t)(b * NH_ + h) * 480 * 128};
    const int*   offp = &s_off[h * 27][0];
    const float* wp   = &s_w[h * 27][s][0];
    float ax = 0.f, ay = 0.f;
#pragma unroll
    for (int l = 0; l < 3; ++l) {
#pragma unroll
        for (int p = 0; p < 9; ++p) {
            int t = l * 9 + p;
            int2 oo = *(const int2*)&offp[t * 2];
            float2 wv = *(const float2*)&wp[t * 4];
            int o0 = __builtin_amdgcn_readfirstlane(oo.x);
            int o1 = __builtin_amdgcn_readfirstlane(oo.y);
            unsigned v0 = *(const unsigned*)(vbs[l] + (size_t)(o0 + lane4));
            unsigned v1 = *(const unsigned*)(vbs[l] + (size_t)(o1 + lane4));
            float lo0 = __uint_as_float(v0 << 16), hi0 = __uint_as_float(v0 & 0xffff0000u);
            float lo1 = __uint_as_float(v1 << 16), hi1 = __uint_as_float(v1 & 0xffff0000u);
            ax += wv.x * lo0 + wv.y * lo1;
            ay += wv.x * hi0 + wv.y * hi1;
        }
    }
    ax += __shfl_xor(ax, 32, 64);
    ay += __shfl_xor(ay, 32, 64);
    if (lane < 32) {
        unsigned pack = (unsigned)f2bf(ax) | ((unsigned)f2bf(ay) << 16);
        *(unsigned*)&mid[(size_t)bq * 384 + h * DH_ + 2 * lane] = pack;
    }
}

// ============ out GEMM: out[m, n] = mid[m,:] @ WoutT[n,:]^T + bout ============
__global__ __launch_bounds__(256) void out_gemm(const unsigned short* __restrict__ mid,
                                                const unsigned short* __restrict__ woT,
                                                const float* __restrict__ bout,
                                                float* __restrict__ out) {
    __shared__ short A[128][40];
    __shared__ short B[128][40];
    const int tid = threadIdx.x;
    const int m0 = blockIdx.x * 128, n0 = blockIdx.y * 128;
    const int lane = tid & 63, wave = tid >> 6;
    const int wm = (wave & 1) * 64, wn = (wave >> 1) * 64;
    float4v acc[4][4];
#pragma unroll
    for (int i = 0; i < 4; ++i)
#pragma unroll
        for (int j = 0; j < 4; ++j) acc[i][j] = (float4v){0.f, 0.f, 0.f, 0.f};

    for (int k0 = 0; k0 < 384; k0 += 32) {
#pragma unroll
        for (int it = 0; it < 2; ++it) {
            int idx = tid + it * 256;
            int r = idx >> 2, sg = idx & 3;
            *(short8*)&A[r][sg * 8] = *(const short8*)&mid[(size_t)(m0 + r) * 384 + k0 + sg * 8];
            *(short8*)&B[r][sg * 8] = *(const short8*)&woT[(size_t)(n0 + r) * 384 + k0 + sg * 8];
        }
        __syncthreads();
        mfma_block(A, B, wm, wn, lane, acc);
        __syncthreads();
    }
    int colb = n0 + wn + (lane & 15);
    int rowq = (lane >> 4) * 4;
#pragma unroll
    for (int i = 0; i < 4; ++i)
#pragma unroll
        for (int j = 0; j < 4; ++j) {
            int n = colb + j * 16;
            float bias = bout[n];
#pragma unroll
            for (int r = 0; r < 4; ++r) {
                int m = m0 + wm + i * 16 + rowq + r;
                out[(size_t)m * 256 + n] = acc[i][j][r] + bias;
            }
        }
}

extern "C" void kernel_launch(void* const* d_in, const int* in_sizes, int n_in,
                              void* d_out, int out_size, void* d_ws, size_t ws_size,
                              hipStream_t stream) {
    const float* x      = (const float*)d_in[0];
    const float* pe     = (const float*)d_in[1];
    const float* coor   = (const float*)d_in[2];
    const float* c2i    = (const float*)d_in[3];
    const float* l2c    = (const float*)d_in[4];
    const float* feat0  = (const float*)d_in[5];
    const float* feat1  = (const float*)d_in[6];
    const float* feat2  = (const float*)d_in[7];
    const float* Wv     = (const float*)d_in[8];
    const float* bv     = (const float*)d_in[9];
    const float* Woff   = (const float*)d_in[10];
    const float* boff   = (const float*)d_in[11];
    const float* Wattn  = (const float*)d_in[12];
    const float* battn  = (const float*)d_in[13];
    const float* Wout   = (const float*)d_in[14];
    const float* bout   = (const float*)d_in[15];

    unsigned short* vws = (unsigned short*)d_ws;
    float* qraw         = (float*)((char*)d_ws + QRAW_BYTE_OFF);
    unsigned short* mid = (unsigned short*)((char*)d_ws + MID_BYTE_OFF);
    unsigned short* wT  = (unsigned short*)((char*)d_ws + WT_BYTE_OFF);
    unsigned short* fT  = (unsigned short*)((char*)d_ws + FEATT_BYTE_OFF);
    float* out          = (float*)d_out;

    prep_all<<<dim3(6166), 256, 0, stream>>>(Wv, Woff, Wattn, Wout, feat0, feat1, feat2, wT, fT);
    gemm_vq<<<dim3(986), 256, 0, stream>>>(fT, wT, bv, vws, x, pe, boff, battn, qraw);
    sample_kernel<<<dim3(BATCH * NQ_), 384, 0, stream>>>(qraw, coor, c2i, l2c, vws, mid);
    out_gemm<<<dim3(128, 2), 256, 0, stream>>>(mid, wT + WOUTT_OFF, bout, out);
}

// Round 4
// 254.505 us; speedup vs baseline: 2.8425x; 1.0153x over previous
//
#include <hip/hip_runtime.h>
#include <hip/hip_bf16.h>

#define NQ_   8192
#define DM_   256
#define NH_   6
#define DH_   64
#define BATCH 2

typedef __attribute__((ext_vector_type(8))) short short8;
typedef __attribute__((ext_vector_type(4))) short short4v;
typedef __attribute__((ext_vector_type(4))) float float4v;

// ---------------- workspace layout ----------------
static const size_t VOFF_L0 = 0;
static const size_t VOFF_L1 = 5898240;
static const size_t VOFF_L2 = 7372800;
static const size_t QRAW_BYTE_OFF  = 15482880;
static const size_t MID_BYTE_OFF   = 47333376;   // mid bf16 [16384][384]
static const size_t QBF_BYTE_OFF   = 47333376;   // qbf bf16 [16384][256] — aliases mid (dead ranges don't overlap in time)
static const size_t WT_BYTE_OFF    = 59916288;
static const size_t FEATT_BYTE_OFF = 60558336;
// wT element offsets
static const size_t WVT_OFF   = 0;        // 384 rows x 256
static const size_t WOFFT_OFF = 98304;    // 324 rows x 256
static const size_t WOUTT_OFF = 222720;   // 256 rows x 384
// featT element offsets
static const size_t FT_L0 = 0;
static const size_t FT_L1 = 3932160;
static const size_t FT_L2 = 4915200;

__device__ __forceinline__ unsigned short f2bf(float f) {
    unsigned int u = __float_as_uint(f);
    unsigned int r = (u + 0x7fffu + ((u >> 16) & 1u)) >> 16;
    return (unsigned short)r;
}

// ============ prep_all: weights T (0..1125) | feat T (1126..6165) | qbf = bf16(x+pe) (6166..7189) ============
__global__ __launch_bounds__(256) void prep_all(const float* __restrict__ Wv,
                                                const float* __restrict__ Woff,
                                                const float* __restrict__ Wattn,
                                                const float* __restrict__ Wout,
                                                const float* __restrict__ feat0,
                                                const float* __restrict__ feat1,
                                                const float* __restrict__ feat2,
                                                const float* __restrict__ x,
                                                const float* __restrict__ pe,
                                                unsigned short* __restrict__ wT,
                                                unsigned short* __restrict__ fT,
                                                unsigned short* __restrict__ qbf) {
    const int pid = blockIdx.x, t = threadIdx.x;
    if (pid < 1126) {
        int r = pid;
        const float* src; int N, n, K; size_t doff;
        if (r < 384)      { src = Wv;    N = 384; n = r;       K = 256; doff = (size_t)r * 256; }
        else if (r < 708) { src = Woff;  N = 324; n = r - 384; K = 256; doff = (size_t)r * 256; }
        else if (r < 870) { src = Wattn; N = 162; n = r - 708; K = 256; doff = (size_t)r * 256; }
        else              { src = Wout;  N = 256; n = r - 870; K = 384; doff = WOUTT_OFF + (size_t)(r - 870) * 384; }
        for (int k = t; k < K; k += 256) wT[doff + k] = f2bf(src[(size_t)k * N + n]);
        return;
    }
    if (pid < 6166) {
        __shared__ float tile[32][33];
        int f = pid - 1126;
        const float* src; unsigned short* dst; int HW;
        if (f < 3840)      { src = feat0; dst = fT + FT_L0; HW = 7680; }
        else if (f < 4800) { src = feat1; dst = fT + FT_L1; HW = 1920; f -= 3840; }
        else               { src = feat2; dst = fT + FT_L2; HW = 480;  f -= 4800; }
        int pb = f >> 4, rem = f & 15, cb = rem >> 1, b = rem & 1;
        int p0 = pb * 32, c0 = cb * 32;
        int tx = t & 31, ty = t >> 5;
#pragma unroll
        for (int i = 0; i < 4; ++i) {
            int c = c0 + ty + i * 8;
            tile[ty + i * 8][tx] = src[((size_t)(b * DM_ + c)) * HW + p0 + tx];
        }
        __syncthreads();
#pragma unroll
        for (int i = 0; i < 4; ++i) {
            int p = p0 + ty + i * 8;
            dst[((size_t)b * HW + p) * DM_ + c0 + tx] = f2bf(tile[tx][ty + i * 8]);
        }
        return;
    }
    // qbf: 1024 blocks, 4096 elements each
    int f = pid - 6166;
#pragma unroll
    for (int i = 0; i < 4; ++i) {
        size_t e = (size_t)f * 4096 + i * 1024 + t * 4;
        float4 xv = *(const float4*)&x[e];
        float4 pv = *(const float4*)&pe[e];
        short4v o;
        o[0] = (short)f2bf(xv.x + pv.x);
        o[1] = (short)f2bf(xv.y + pv.y);
        o[2] = (short)f2bf(xv.z + pv.z);
        o[3] = (short)f2bf(xv.w + pv.w);
        *(short4v*)&qbf[e] = o;
    }
}

// ============ shared MFMA inner block: 128x128 tile, 4 waves 2x2, 4x4 frags ============
__device__ __forceinline__ void mfma_block(const short A[][40], const short B[][40],
                                           int wm, int wn, int lane, float4v acc[4][4]) {
    int m_base = wm + (lane & 15);
    int n_base = wn + (lane & 15);
    int q8 = (lane >> 4) * 8;
    short8 af[4], bf[4];
#pragma unroll
    for (int i = 0; i < 4; ++i) af[i] = *(const short8*)&A[m_base + i * 16][q8];
#pragma unroll
    for (int j = 0; j < 4; ++j) bf[j] = *(const short8*)&B[n_base + j * 16][q8];
#pragma unroll
    for (int i = 0; i < 4; ++i)
#pragma unroll
        for (int j = 0; j < 4; ++j)
            acc[i][j] = __builtin_amdgcn_mfma_f32_16x16x32_bf16(af[i], bf[j], acc[i][j], 0, 0, 0);
}

// ============ fused value GEMM (blocks 0..473) + query GEMM (blocks 474..985) ============
__global__ __launch_bounds__(256) void gemm_vq(const unsigned short* __restrict__ fT,
                                               const unsigned short* __restrict__ wT,
                                               const float* __restrict__ bv,
                                               unsigned short* __restrict__ vws,
                                               const unsigned short* __restrict__ qbf,
                                               const float* __restrict__ boff,
                                               const float* __restrict__ battn,
                                               float* __restrict__ qraw) {
    __shared__ short A[128][40];
    __shared__ short B[128][40];
    const int tid = threadIdx.x;
    const int lane = tid & 63, wave = tid >> 6;
    const int wm = (wave & 1) * 64, wn = (wave >> 1) * 64;
    const int id = blockIdx.x;
    float4v acc[4][4];
#pragma unroll
    for (int i = 0; i < 4; ++i)
#pragma unroll
        for (int j = 0; j < 4; ++j) acc[i][j] = (float4v){0.f, 0.f, 0.f, 0.f};

    if (id < 474) {
        // ---- value path ----
        int pb = id / 6, rem = id % 6;
        int nb = rem >> 1, b = rem & 1;
        int pbl, HW; size_t ftoff, voff;
        if (pb < 60)      { pbl = pb;      HW = 7680; ftoff = FT_L0; voff = VOFF_L0; }
        else if (pb < 75) { pbl = pb - 60; HW = 1920; ftoff = FT_L1; voff = VOFF_L1; }
        else              { pbl = pb - 75; HW = 480;  ftoff = FT_L2; voff = VOFF_L2; }
        const int p0 = pbl * 128, n0 = nb * 128;
        const unsigned short* Asrc = fT + ftoff + (size_t)b * HW * DM_;
        const unsigned short* wvT = wT + WVT_OFF;

        for (int k0 = 0; k0 < DM_; k0 += 32) {
#pragma unroll
            for (int it = 0; it < 2; ++it) {
                int idx = tid + it * 256;
                int r = idx >> 2, sg = idx & 3;
                int p = p0 + r; if (p >= HW) p = HW - 1;
                *(short8*)&A[r][sg * 8] = *(const short8*)&Asrc[(size_t)p * DM_ + k0 + sg * 8];
                *(short8*)&B[r][sg * 8] = *(const short8*)&wvT[(size_t)(n0 + r) * DM_ + k0 + sg * 8];
            }
            __syncthreads();
            mfma_block(A, B, wm, wn, lane, acc);
            __syncthreads();
        }
        int colb = n0 + wn + (lane & 15);
        int rowq = (lane >> 4) * 4;
#pragma unroll
        for (int i = 0; i < 4; ++i)
#pragma unroll
            for (int j = 0; j < 4; ++j) {
                int n = colb + j * 16;
                int h = n >> 6, d = n & 63;
                float bias = bv[n];
#pragma unroll
                for (int r = 0; r < 4; ++r) {
                    int p = p0 + wm + i * 16 + rowq + r;
                    if (p < HW)
                        vws[voff + ((size_t)(b * NH_ + h) * HW + p) * DH_ + d] = f2bf(acc[i][j][r] + bias);
                }
            }
    } else {
        // ---- query path (bf16 staging from qbf) ----
        int qid = id - 474;
        const int m0 = (qid & 127) * 128, n0 = (qid >> 7) * 128;
        for (int k0 = 0; k0 < DM_; k0 += 32) {
#pragma unroll
            for (int it = 0; it < 2; ++it) {
                int idx = tid + it * 256;
                int r = idx >> 2, sg = idx & 3;
                *(short8*)&A[r][sg * 8] = *(const short8*)&qbf[(size_t)(m0 + r) * DM_ + k0 + sg * 8];
                int g = n0 + r;
                short8 bz = (short8)0;
                if (g < 486) bz = *(const short8*)&wT[WOFFT_OFF + (size_t)g * DM_ + k0 + sg * 8];
                *(short8*)&B[r][sg * 8] = bz;
            }
            __syncthreads();
            mfma_block(A, B, wm, wn, lane, acc);
            __syncthreads();
        }
        int colb = n0 + wn + (lane & 15);
        int rowq = (lane >> 4) * 4;
#pragma unroll
        for (int i = 0; i < 4; ++i)
#pragma unroll
            for (int j = 0; j < 4; ++j) {
                int n = colb + j * 16;
                if (n < 486) {
                    float bias = (n < 324) ? boff[n] : battn[n - 324];
#pragma unroll
                    for (int r = 0; r < 4; ++r) {
                        int m = m0 + wm + i * 16 + rowq + r;
                        qraw[(size_t)m * 486 + n] = acc[i][j][r] + bias;
                    }
                }
            }
    }
}

// ============ fused softmax + projection + half-wave dwordx2 gather ============
// wave h = head h; lanes 0-31 = y-row0, 32-63 = y-row1; lane>>4 selects (y,x-slot) weight;
// lane&15 = channel quad. One dwordx2 load per tap per wave.
__global__ __launch_bounds__(384) void sample_kernel(const float* __restrict__ qraw,
                                                     const float* __restrict__ coor,
                                                     const float* __restrict__ cam2img,
                                                     const float* __restrict__ l2c,
                                                     const unsigned short* __restrict__ vws,
                                                     unsigned short* __restrict__ mid) {
    __shared__ int   s_off2[162][2];   // absolute byte offsets into vws, per y-row
    __shared__ float s_wt[162][4];     // [tap][(y<<1)|xslot]
    const int tid = threadIdx.x;
    const int bq = blockIdx.x;
    const int b = bq >> 13;

    if (tid < 192) {
        int h = tid >> 5, j = tid & 31;
        bool act = j < 27;
        float logit = act ? qraw[(size_t)bq * 486 + 324 + h * 27 + j] : -1e30f;
        float m = logit;
#pragma unroll
        for (int msk = 16; msk >= 1; msk >>= 1) m = fmaxf(m, __shfl_xor(m, msk, 32));
        float e = act ? __expf(logit - m) : 0.f;
        float ssum = e;
#pragma unroll
        for (int msk = 16; msk >= 1; msk >>= 1) ssum += __shfl_xor(ssum, msk, 32);
        if (act) {
            float attn = e * __frcp_rn(ssum);
            int l = (j >= 18) ? 2 : ((j >= 9) ? 1 : 0);
            int wl = 160 >> l, hl = 48 >> l;
            int HWl = (l == 0) ? 7680 : ((l == 1) ? 1920 : 480);
            int lvlb = (l == 0) ? 0 : ((l == 1) ? 11796480 : 14745600);
            float sc = (l == 0) ? 0.125f : ((l == 1) ? 0.0625f : 0.03125f);
            float c0 = coor[(size_t)bq * 3 + 0];
            float c1 = coor[(size_t)bq * 3 + 1];
            float c2 = coor[(size_t)bq * 3 + 2];
            const float* L = l2c + b * 16;
            const float* C = cam2img + b * 16;
            float pc0 = L[0] * c0 + L[1] * c1 + L[2]  * c2 + L[3];
            float pc1 = L[4] * c0 + L[5] * c1 + L[6]  * c2 + L[7];
            float pc2 = L[8] * c0 + L[9] * c1 + L[10] * c2 + L[11];
            float q0 = C[0] * pc0 + C[1] * pc1 + C[2]  * pc2 + C[3];
            float q1 = C[4] * pc0 + C[5] * pc1 + C[6]  * pc2 + C[7];
            float q2 = C[8] * pc0 + C[9] * pc1 + C[10] * pc2 + C[11];
            float u = q0 / q2, v = q1 / q2;
            float refx = u * sc, refy = v * sc;
            float ox = qraw[(size_t)bq * 486 + h * 54 + j * 2];
            float oy = qraw[(size_t)bq * 486 + h * 54 + j * 2 + 1];
            float X = refx + ox - 0.5f;
            float Y = refy + oy - 0.5f;
            float x0f = floorf(X), y0f = floorf(Y);
            float fx = X - x0f, fy = Y - y0f;
            int ix = (int)x0f, iy = (int)y0f;
            int bx = min(max(ix, 0), wl - 2);
            float wx0 = ((bx == ix) ? (1.f - fx) : 0.f) + ((bx == ix + 1) ? fx : 0.f);
            float wx1 = ((bx + 1 == ix) ? (1.f - fx) : 0.f) + ((bx + 1 == ix + 1) ? fx : 0.f);
            int cy0 = min(max(iy, 0), hl - 1);
            int cy1 = min(max(iy + 1, 0), hl - 1);
            float wy0 = (iy >= 0 && iy < hl) ? (1.f - fy) : 0.f;
            float wy1 = (iy + 1 >= 0 && iy + 1 < hl) ? fy : 0.f;
            int jj = h * 27 + j;
            int slice = (b * NH_ + h) * HWl;
            s_off2[jj][0] = lvlb + (slice + cy0 * wl + bx) * 128;
            s_off2[jj][1] = lvlb + (slice + cy1 * wl + bx) * 128;
            s_wt[jj][0] = attn * wy0 * wx0;
            s_wt[jj][1] = attn * wy0 * wx1;
            s_wt[jj][2] = attn * wy1 * wx0;
            s_wt[jj][3] = attn * wy1 * wx1;
        }
    }
    __syncthreads();

    const int h = tid >> 6;
    const int lane = tid & 63;
    const int osel = lane >> 5;
    const int wsel = lane >> 4;
    const char* vbl = (const char*)vws + ((lane & 31) << 3);
    const int*   op = &s_off2[h * 27][0];
    const float* wp = &s_wt[h * 27][0];
    float a0 = 0.f, a1 = 0.f, a2 = 0.f, a3 = 0.f;
#pragma unroll
    for (int t = 0; t < 27; ++t) {
        int   off = op[t * 2 + osel];
        float w   = wp[t * 4 + wsel];
        uint2 d = *(const uint2*)(vbl + off);
        a0 = fmaf(w, __uint_as_float(d.x << 16), a0);
        a1 = fmaf(w, __uint_as_float(d.x & 0xffff0000u), a1);
        a2 = fmaf(w, __uint_as_float(d.y << 16), a2);
        a3 = fmaf(w, __uint_as_float(d.y & 0xffff0000u), a3);
    }
    a0 += __shfl_xor(a0, 16, 64);
    a1 += __shfl_xor(a1, 16, 64);
    a2 += __shfl_xor(a2, 16, 64);
    a3 += __shfl_xor(a3, 16, 64);
    a0 += __shfl_xor(a0, 32, 64);
    a1 += __shfl_xor(a1, 32, 64);
    a2 += __shfl_xor(a2, 32, 64);
    a3 += __shfl_xor(a3, 32, 64);
    if (lane < 16) {
        unsigned lo = (unsigned)f2bf(a0) | ((unsigned)f2bf(a1) << 16);
        unsigned hi = (unsigned)f2bf(a2) | ((unsigned)f2bf(a3) << 16);
        uint2 pk; pk.x = lo; pk.y = hi;
        *(uint2*)&mid[(size_t)bq * 384 + h * DH_ + (lane << 2)] = pk;
    }
}

// ============ out GEMM: out[m, n] = mid[m,:] @ WoutT[n,:]^T + bout ============
__global__ __launch_bounds__(256) void out_gemm(const unsigned short* __restrict__ mid,
                                                const unsigned short* __restrict__ woT,
                                                const float* __restrict__ bout,
                                                float* __restrict__ out) {
    __shared__ short A[128][40];
    __shared__ short B[128][40];
    const int tid = threadIdx.x;
    const int m0 = blockIdx.x * 128, n0 = blockIdx.y * 128;
    const int lane = tid & 63, wave = tid >> 6;
    const int wm = (wave & 1) * 64, wn = (wave >> 1) * 64;
    float4v acc[4][4];
#pragma unroll
    for (int i = 0; i < 4; ++i)
#pragma unroll
        for (int j = 0; j < 4; ++j) acc[i][j] = (float4v){0.f, 0.f, 0.f, 0.f};

    for (int k0 = 0; k0 < 384; k0 += 32) {
#pragma unroll
        for (int it = 0; it < 2; ++it) {
            int idx = tid + it * 256;
            int r = idx >> 2, sg = idx & 3;
            *(short8*)&A[r][sg * 8] = *(const short8*)&mid[(size_t)(m0 + r) * 384 + k0 + sg * 8];
            *(short8*)&B[r][sg * 8] = *(const short8*)&woT[(size_t)(n0 + r) * 384 + k0 + sg * 8];
        }
        __syncthreads();
        mfma_block(A, B, wm, wn, lane, acc);
        __syncthreads();
    }
    int colb = n0 + wn + (lane & 15);
    int rowq = (lane >> 4) * 4;
#pragma unroll
    for (int i = 0; i < 4; ++i)
#pragma unroll
        for (int j = 0; j < 4; ++j) {
            int n = colb + j * 16;
            float bias = bout[n];
#pragma unroll
            for (int r = 0; r < 4; ++r) {
                int m = m0 + wm + i * 16 + rowq + r;
                out[(size_t)m * 256 + n] = acc[i][j][r] + bias;
            }
        }
}

extern "C" void kernel_launch(void* const* d_in, const int* in_sizes, int n_in,
                              void* d_out, int out_size, void* d_ws, size_t ws_size,
                              hipStream_t stream) {
    const float* x      = (const float*)d_in[0];
    const float* pe     = (const float*)d_in[1];
    const float* coor   = (const float*)d_in[2];
    const float* c2i    = (const float*)d_in[3];
    const float* l2c    = (const float*)d_in[4];
    const float* feat0  = (const float*)d_in[5];
    const float* feat1  = (const float*)d_in[6];
    const float* feat2  = (const float*)d_in[7];
    const float* Wv     = (const float*)d_in[8];
    const float* bv     = (const float*)d_in[9];
    const float* Woff   = (const float*)d_in[10];
    const float* boff   = (const float*)d_in[11];
    const float* Wattn  = (const float*)d_in[12];
    const float* battn  = (const float*)d_in[13];
    const float* Wout   = (const float*)d_in[14];
    const float* bout   = (const float*)d_in[15];

    unsigned short* vws = (unsigned short*)d_ws;
    float* qraw         = (float*)((char*)d_ws + QRAW_BYTE_OFF);
    unsigned short* mid = (unsigned short*)((char*)d_ws + MID_BYTE_OFF);
    unsigned short* qbf = (unsigned short*)((char*)d_ws + QBF_BYTE_OFF);
    unsigned short* wT  = (unsigned short*)((char*)d_ws + WT_BYTE_OFF);
    unsigned short* fT  = (unsigned short*)((char*)d_ws + FEATT_BYTE_OFF);
    float* out          = (float*)d_out;

    prep_all<<<dim3(7190), 256, 0, stream>>>(Wv, Woff, Wattn, Wout, feat0, feat1, feat2,
                                             x, pe, wT, fT, qbf);
    gemm_vq<<<dim3(986), 256, 0, stream>>>(fT, wT, bv, vws, qbf, boff, battn, qraw);
    sample_kernel<<<dim3(BATCH * NQ_), 384, 0, stream>>>(qraw, coor, c2i, l2c, vws, mid);
    out_gemm<<<dim3(128, 2), 256, 0, stream>>>(mid, wT + WOUTT_OFF, bout, out);
}

// Round 5
// 245.574 us; speedup vs baseline: 2.9459x; 1.0364x over previous
//
#include <hip/hip_runtime.h>
#include <hip/hip_bf16.h>

#define NQ_   8192
#define DM_   256
#define NH_   6
#define DH_   64
#define BATCH 2

typedef __attribute__((ext_vector_type(8))) short short8;
typedef __attribute__((ext_vector_type(4))) short short4v;
typedef __attribute__((ext_vector_type(4))) float float4v;

// ---------------- workspace layout ----------------
static const size_t VOFF_L0 = 0;
static const size_t VOFF_L1 = 5898240;
static const size_t VOFF_L2 = 7372800;
static const size_t QRAW_BYTE_OFF  = 15482880;
static const size_t MID_BYTE_OFF   = 47333376;   // mid bf16 [16384][384]
static const size_t QBF_BYTE_OFF   = 47333376;   // qbf bf16 [16384][256] — aliases mid (lifetimes disjoint)
static const size_t WT_BYTE_OFF    = 59916288;
static const size_t FEATT_BYTE_OFF = 60558336;
// wT element offsets
static const size_t WVT_OFF   = 0;        // 384 rows x 256
static const size_t WOFFT_OFF = 98304;    // 324 rows x 256
static const size_t WOUTT_OFF = 222720;   // 256 rows x 384
// featT element offsets
static const size_t FT_L0 = 0;
static const size_t FT_L1 = 3932160;
static const size_t FT_L2 = 4915200;

__device__ __forceinline__ unsigned short f2bf(float f) {
    unsigned int u = __float_as_uint(f);
    unsigned int r = (u + 0x7fffu + ((u >> 16) & 1u)) >> 16;
    return (unsigned short)r;
}

// ============ prep_all: weights T (0..1125) | feat T (1126..6165) | qbf = bf16(x+pe) (6166..7189) ============
__global__ __launch_bounds__(256) void prep_all(const float* __restrict__ Wv,
                                                const float* __restrict__ Woff,
                                                const float* __restrict__ Wattn,
                                                const float* __restrict__ Wout,
                                                const float* __restrict__ feat0,
                                                const float* __restrict__ feat1,
                                                const float* __restrict__ feat2,
                                                const float* __restrict__ x,
                                                const float* __restrict__ pe,
                                                unsigned short* __restrict__ wT,
                                                unsigned short* __restrict__ fT,
                                                unsigned short* __restrict__ qbf) {
    const int pid = blockIdx.x, t = threadIdx.x;
    if (pid < 1126) {
        int r = pid;
        const float* src; int N, n, K; size_t doff;
        if (r < 384)      { src = Wv;    N = 384; n = r;       K = 256; doff = (size_t)r * 256; }
        else if (r < 708) { src = Woff;  N = 324; n = r - 384; K = 256; doff = (size_t)r * 256; }
        else if (r < 870) { src = Wattn; N = 162; n = r - 708; K = 256; doff = (size_t)r * 256; }
        else              { src = Wout;  N = 256; n = r - 870; K = 384; doff = WOUTT_OFF + (size_t)(r - 870) * 384; }
        for (int k = t; k < K; k += 256) wT[doff + k] = f2bf(src[(size_t)k * N + n]);
        return;
    }
    if (pid < 6166) {
        __shared__ float tile[32][33];
        int f = pid - 1126;
        const float* src; unsigned short* dst; int HW;
        if (f < 3840)      { src = feat0; dst = fT + FT_L0; HW = 7680; }
        else if (f < 4800) { src = feat1; dst = fT + FT_L1; HW = 1920; f -= 3840; }
        else               { src = feat2; dst = fT + FT_L2; HW = 480;  f -= 4800; }
        int pb = f >> 4, rem = f & 15, cb = rem >> 1, b = rem & 1;
        int p0 = pb * 32, c0 = cb * 32;
        int tx = t & 31, ty = t >> 5;
#pragma unroll
        for (int i = 0; i < 4; ++i) {
            int c = c0 + ty + i * 8;
            tile[ty + i * 8][tx] = src[((size_t)(b * DM_ + c)) * HW + p0 + tx];
        }
        __syncthreads();
#pragma unroll
        for (int i = 0; i < 4; ++i) {
            int p = p0 + ty + i * 8;
            dst[((size_t)b * HW + p) * DM_ + c0 + tx] = f2bf(tile[tx][ty + i * 8]);
        }
        return;
    }
    // qbf: 1024 blocks, 4096 elements each
    int f = pid - 6166;
#pragma unroll
    for (int i = 0; i < 4; ++i) {
        size_t e = (size_t)f * 4096 + i * 1024 + t * 4;
        float4 xv = *(const float4*)&x[e];
        float4 pv = *(const float4*)&pe[e];
        short4v o;
        o[0] = (short)f2bf(xv.x + pv.x);
        o[1] = (short)f2bf(xv.y + pv.y);
        o[2] = (short)f2bf(xv.z + pv.z);
        o[3] = (short)f2bf(xv.w + pv.w);
        *(short4v*)&qbf[e] = o;
    }
}

// ============ shared MFMA inner block: 128x128 tile, 4 waves 2x2, 4x4 frags ============
__device__ __forceinline__ void mfma_block(const short A[][40], const short B[][40],
                                           int wm, int wn, int lane, float4v acc[4][4]) {
    int m_base = wm + (lane & 15);
    int n_base = wn + (lane & 15);
    int q8 = (lane >> 4) * 8;
    short8 af[4], bf[4];
#pragma unroll
    for (int i = 0; i < 4; ++i) af[i] = *(const short8*)&A[m_base + i * 16][q8];
#pragma unroll
    for (int j = 0; j < 4; ++j) bf[j] = *(const short8*)&B[n_base + j * 16][q8];
#pragma unroll
    for (int i = 0; i < 4; ++i)
#pragma unroll
        for (int j = 0; j < 4; ++j)
            acc[i][j] = __builtin_amdgcn_mfma_f32_16x16x32_bf16(af[i], bf[j], acc[i][j], 0, 0, 0);
}

// ============ fused value GEMM (blocks 0..473) + query GEMM (blocks 474..985) ============
__global__ __launch_bounds__(256) void gemm_vq(const unsigned short* __restrict__ fT,
                                               const unsigned short* __restrict__ wT,
                                               const float* __restrict__ bv,
                                               unsigned short* __restrict__ vws,
                                               const unsigned short* __restrict__ qbf,
                                               const float* __restrict__ boff,
                                               const float* __restrict__ battn,
                                               float* __restrict__ qraw) {
    __shared__ short A[128][40];
    __shared__ short B[128][40];
    const int tid = threadIdx.x;
    const int lane = tid & 63, wave = tid >> 6;
    const int wm = (wave & 1) * 64, wn = (wave >> 1) * 64;
    const int id = blockIdx.x;
    float4v acc[4][4];
#pragma unroll
    for (int i = 0; i < 4; ++i)
#pragma unroll
        for (int j = 0; j < 4; ++j) acc[i][j] = (float4v){0.f, 0.f, 0.f, 0.f};

    if (id < 474) {
        // ---- value path ----
        int pb = id / 6, rem = id % 6;
        int nb = rem >> 1, b = rem & 1;
        int pbl, HW; size_t ftoff, voff;
        if (pb < 60)      { pbl = pb;      HW = 7680; ftoff = FT_L0; voff = VOFF_L0; }
        else if (pb < 75) { pbl = pb - 60; HW = 1920; ftoff = FT_L1; voff = VOFF_L1; }
        else              { pbl = pb - 75; HW = 480;  ftoff = FT_L2; voff = VOFF_L2; }
        const int p0 = pbl * 128, n0 = nb * 128;
        const unsigned short* Asrc = fT + ftoff + (size_t)b * HW * DM_;
        const unsigned short* wvT = wT + WVT_OFF;

        for (int k0 = 0; k0 < DM_; k0 += 32) {
#pragma unroll
            for (int it = 0; it < 2; ++it) {
                int idx = tid + it * 256;
                int r = idx >> 2, sg = idx & 3;
                int p = p0 + r; if (p >= HW) p = HW - 1;
                *(short8*)&A[r][sg * 8] = *(const short8*)&Asrc[(size_t)p * DM_ + k0 + sg * 8];
                *(short8*)&B[r][sg * 8] = *(const short8*)&wvT[(size_t)(n0 + r) * DM_ + k0 + sg * 8];
            }
            __syncthreads();
            mfma_block(A, B, wm, wn, lane, acc);
            __syncthreads();
        }
        int colb = n0 + wn + (lane & 15);
        int rowq = (lane >> 4) * 4;
#pragma unroll
        for (int i = 0; i < 4; ++i)
#pragma unroll
            for (int j = 0; j < 4; ++j) {
                int n = colb + j * 16;
                int h = n >> 6, d = n & 63;
                float bias = bv[n];
#pragma unroll
                for (int r = 0; r < 4; ++r) {
                    int p = p0 + wm + i * 16 + rowq + r;
                    if (p < HW)
                        vws[voff + ((size_t)(b * NH_ + h) * HW + p) * DH_ + d] = f2bf(acc[i][j][r] + bias);
                }
            }
    } else {
        // ---- query path (bf16 staging from qbf) ----
        int qid = id - 474;
        const int m0 = (qid & 127) * 128, n0 = (qid >> 7) * 128;
        for (int k0 = 0; k0 < DM_; k0 += 32) {
#pragma unroll
            for (int it = 0; it < 2; ++it) {
                int idx = tid + it * 256;
                int r = idx >> 2, sg = idx & 3;
                *(short8*)&A[r][sg * 8] = *(const short8*)&qbf[(size_t)(m0 + r) * DM_ + k0 + sg * 8];
                int g = n0 + r;
                short8 bz = (short8)0;
                if (g < 486) bz = *(const short8*)&wT[WOFFT_OFF + (size_t)g * DM_ + k0 + sg * 8];
                *(short8*)&B[r][sg * 8] = bz;
            }
            __syncthreads();
            mfma_block(A, B, wm, wn, lane, acc);
            __syncthreads();
        }
        int colb = n0 + wn + (lane & 15);
        int rowq = (lane >> 4) * 4;
#pragma unroll
        for (int i = 0; i < 4; ++i)
#pragma unroll
            for (int j = 0; j < 4; ++j) {
                int n = colb + j * 16;
                if (n < 486) {
                    float bias = (n < 324) ? boff[n] : battn[n - 324];
#pragma unroll
                    for (int r = 0; r < 4; ++r) {
                        int m = m0 + wm + i * 16 + rowq + r;
                        qraw[(size_t)m * 486 + n] = acc[i][j][r] + bias;
                    }
                }
            }
    }
}

// ============ fused softmax + projection + gather, 2 queries per block ============
// setup: tid<192 -> query0, tid>=192 -> query1; within 192: h = t>>5 (32-lane softmax groups)
// gather: wave h handles head h for both queries, taps interleaved
// plan LDS: s_plan[q][h*27+tap][wsel] = {byte_off(ypix=wsel>>1), bits(w[wsel])}
__global__ __launch_bounds__(384) void sample_kernel(const float* __restrict__ qraw,
                                                     const float* __restrict__ coor,
                                                     const float* __restrict__ cam2img,
                                                     const float* __restrict__ l2c,
                                                     const unsigned short* __restrict__ vws,
                                                     unsigned short* __restrict__ mid) {
    __shared__ int2 s_plan[2][162][4];
    const int tid = threadIdx.x;
    const int bq0 = blockIdx.x * 2;

    {
        int q = tid >= 192;
        int t = tid - q * 192;
        int bq = bq0 + q;
        int b = bq >> 13;
        int h = t >> 5, j = t & 31;
        bool act = j < 27;
        float logit = act ? qraw[(size_t)bq * 486 + 324 + h * 27 + j] : -1e30f;
        float m = logit;
#pragma unroll
        for (int msk = 16; msk >= 1; msk >>= 1) m = fmaxf(m, __shfl_xor(m, msk, 32));
        float e = act ? __expf(logit - m) : 0.f;
        float ssum = e;
#pragma unroll
        for (int msk = 16; msk >= 1; msk >>= 1) ssum += __shfl_xor(ssum, msk, 32);
        if (act) {
            float attn = e * __frcp_rn(ssum);
            int l = (j >= 18) ? 2 : ((j >= 9) ? 1 : 0);
            int wl = 160 >> l, hl = 48 >> l;
            int HWl = (l == 0) ? 7680 : ((l == 1) ? 1920 : 480);
            int lvlb = (l == 0) ? 0 : ((l == 1) ? 11796480 : 14745600);
            float sc = (l == 0) ? 0.125f : ((l == 1) ? 0.0625f : 0.03125f);
            float c0 = coor[(size_t)bq * 3 + 0];
            float c1 = coor[(size_t)bq * 3 + 1];
            float c2 = coor[(size_t)bq * 3 + 2];
            const float* L = l2c + b * 16;
            const float* C = cam2img + b * 16;
            float pc0 = L[0] * c0 + L[1] * c1 + L[2]  * c2 + L[3];
            float pc1 = L[4] * c0 + L[5] * c1 + L[6]  * c2 + L[7];
            float pc2 = L[8] * c0 + L[9] * c1 + L[10] * c2 + L[11];
            float q0 = C[0] * pc0 + C[1] * pc1 + C[2]  * pc2 + C[3];
            float q1 = C[4] * pc0 + C[5] * pc1 + C[6]  * pc2 + C[7];
            float q2 = C[8] * pc0 + C[9] * pc1 + C[10] * pc2 + C[11];
            float rz = __frcp_rn(q2);
            float refx = q0 * rz * sc, refy = q1 * rz * sc;
            float2 oxy = *(const float2*)&qraw[(size_t)bq * 486 + h * 54 + j * 2];
            float X = refx + oxy.x - 0.5f;
            float Y = refy + oxy.y - 0.5f;
            float x0f = floorf(X), y0f = floorf(Y);
            float fx = X - x0f, fy = Y - y0f;
            int ix = (int)x0f, iy = (int)y0f;
            int bx = min(max(ix, 0), wl - 2);
            float wx0 = ((bx == ix) ? (1.f - fx) : 0.f) + ((bx == ix + 1) ? fx : 0.f);
            float wx1 = ((bx + 1 == ix) ? (1.f - fx) : 0.f) + ((bx + 1 == ix + 1) ? fx : 0.f);
            int cy0 = min(max(iy, 0), hl - 1);
            int cy1 = min(max(iy + 1, 0), hl - 1);
            float wy0 = (iy >= 0 && iy < hl) ? (1.f - fy) : 0.f;
            float wy1 = (iy + 1 >= 0 && iy + 1 < hl) ? fy : 0.f;
            int jj = h * 27 + j;
            int slice = (b * NH_ + h) * HWl;
            int off0 = lvlb + (slice + cy0 * wl + bx) * 128;
            int off1 = lvlb + (slice + cy1 * wl + bx) * 128;
            s_plan[q][jj][0] = make_int2(off0, __float_as_int(attn * wy0 * wx0));
            s_plan[q][jj][1] = make_int2(off0, __float_as_int(attn * wy0 * wx1));
            s_plan[q][jj][2] = make_int2(off1, __float_as_int(attn * wy1 * wx0));
            s_plan[q][jj][3] = make_int2(off1, __float_as_int(attn * wy1 * wx1));
        }
    }
    __syncthreads();

    const int h = tid >> 6;
    const int lane = tid & 63;
    const unsigned lb = (unsigned)((lane & 31) << 3);
    const char* vbase = (const char*)vws;
    const char* pp0 = (const char*)&s_plan[0][h * 27][lane >> 4];
    const char* pp1 = (const char*)&s_plan[1][h * 27][lane >> 4];
    float b0 = 0.f, b1 = 0.f, b2 = 0.f, b3 = 0.f;
    float c0 = 0.f, c1 = 0.f, c2 = 0.f, c3 = 0.f;
#pragma unroll
    for (int t = 0; t < 27; ++t) {
        int2 ow0 = *(const int2*)(pp0 + t * 32);
        int2 ow1 = *(const int2*)(pp1 + t * 32);
        uint2 d0 = *(const uint2*)(vbase + ((unsigned)ow0.x + lb));
        uint2 d1 = *(const uint2*)(vbase + ((unsigned)ow1.x + lb));
        float w0 = __int_as_float(ow0.y);
        float w1 = __int_as_float(ow1.y);
        b0 = fmaf(w0, __uint_as_float(d0.x << 16), b0);
        b1 = fmaf(w0, __uint_as_float(d0.x & 0xffff0000u), b1);
        b2 = fmaf(w0, __uint_as_float(d0.y << 16), b2);
        b3 = fmaf(w0, __uint_as_float(d0.y & 0xffff0000u), b3);
        c0 = fmaf(w1, __uint_as_float(d1.x << 16), c0);
        c1 = fmaf(w1, __uint_as_float(d1.x & 0xffff0000u), c1);
        c2 = fmaf(w1, __uint_as_float(d1.y << 16), c2);
        c3 = fmaf(w1, __uint_as_float(d1.y & 0xffff0000u), c3);
    }
    b0 += __shfl_xor(b0, 16, 64);  c0 += __shfl_xor(c0, 16, 64);
    b1 += __shfl_xor(b1, 16, 64);  c1 += __shfl_xor(c1, 16, 64);
    b2 += __shfl_xor(b2, 16, 64);  c2 += __shfl_xor(c2, 16, 64);
    b3 += __shfl_xor(b3, 16, 64);  c3 += __shfl_xor(c3, 16, 64);
    b0 += __shfl_xor(b0, 32, 64);  c0 += __shfl_xor(c0, 32, 64);
    b1 += __shfl_xor(b1, 32, 64);  c1 += __shfl_xor(c1, 32, 64);
    b2 += __shfl_xor(b2, 32, 64);  c2 += __shfl_xor(c2, 32, 64);
    b3 += __shfl_xor(b3, 32, 64);  c3 += __shfl_xor(c3, 32, 64);
    if (lane < 16) {
        uint2 pk0, pk1;
        pk0.x = (unsigned)f2bf(b0) | ((unsigned)f2bf(b1) << 16);
        pk0.y = (unsigned)f2bf(b2) | ((unsigned)f2bf(b3) << 16);
        pk1.x = (unsigned)f2bf(c0) | ((unsigned)f2bf(c1) << 16);
        pk1.y = (unsigned)f2bf(c2) | ((unsigned)f2bf(c3) << 16);
        *(uint2*)&mid[(size_t)bq0 * 384 + h * DH_ + (lane << 2)] = pk0;
        *(uint2*)&mid[(size_t)(bq0 + 1) * 384 + h * DH_ + (lane << 2)] = pk1;
    }
}

// ============ out GEMM: out[m, n] = mid[m,:] @ WoutT[n,:]^T + bout ============
__global__ __launch_bounds__(256) void out_gemm(const unsigned short* __restrict__ mid,
                                                const unsigned short* __restrict__ woT,
                                                const float* __restrict__ bout,
                                                float* __restrict__ out) {
    __shared__ short A[128][40];
    __shared__ short B[128][40];
    const int tid = threadIdx.x;
    const int m0 = blockIdx.x * 128, n0 = blockIdx.y * 128;
    const int lane = tid & 63, wave = tid >> 6;
    const int wm = (wave & 1) * 64, wn = (wave >> 1) * 64;
    float4v acc[4][4];
#pragma unroll
    for (int i = 0; i < 4; ++i)
#pragma unroll
        for (int j = 0; j < 4; ++j) acc[i][j] = (float4v){0.f, 0.f, 0.f, 0.f};

    for (int k0 = 0; k0 < 384; k0 += 32) {
#pragma unroll
        for (int it = 0; it < 2; ++it) {
            int idx = tid + it * 256;
            int r = idx >> 2, sg = idx & 3;
            *(short8*)&A[r][sg * 8] = *(const short8*)&mid[(size_t)(m0 + r) * 384 + k0 + sg * 8];
            *(short8*)&B[r][sg * 8] = *(const short8*)&woT[(size_t)(n0 + r) * 384 + k0 + sg * 8];
        }
        __syncthreads();
        mfma_block(A, B, wm, wn, lane, acc);
        __syncthreads();
    }
    int colb = n0 + wn + (lane & 15);
    int rowq = (lane >> 4) * 4;
#pragma unroll
    for (int i = 0; i < 4; ++i)
#pragma unroll
        for (int j = 0; j < 4; ++j) {
            int n = colb + j * 16;
            float bias = bout[n];
#pragma unroll
            for (int r = 0; r < 4; ++r) {
                int m = m0 + wm + i * 16 + rowq + r;
                out[(size_t)m * 256 + n] = acc[i][j][r] + bias;
            }
        }
}

extern "C" void kernel_launch(void* const* d_in, const int* in_sizes, int n_in,
                              void* d_out, int out_size, void* d_ws, size_t ws_size,
                              hipStream_t stream) {
    const float* x      = (const float*)d_in[0];
    const float* pe     = (const float*)d_in[1];
    const float* coor   = (const float*)d_in[2];
    const float* c2i    = (const float*)d_in[3];
    const float* l2c    = (const float*)d_in[4];
    const float* feat0  = (const float*)d_in[5];
    const float* feat1  = (const float*)d_in[6];
    const float* feat2  = (const float*)d_in[7];
    const float* Wv     = (const float*)d_in[8];
    const float* bv     = (const float*)d_in[9];
    const float* Woff   = (const float*)d_in[10];
    const float* boff   = (const float*)d_in[11];
    const float* Wattn  = (const float*)d_in[12];
    const float* battn  = (const float*)d_in[13];
    const float* Wout   = (const float*)d_in[14];
    const float* bout   = (const float*)d_in[15];

    unsigned short* vws = (unsigned short*)d_ws;
    float* qraw         = (float*)((char*)d_ws + QRAW_BYTE_OFF);
    unsigned short* mid = (unsigned short*)((char*)d_ws + MID_BYTE_OFF);
    unsigned short* qbf = (unsigned short*)((char*)d_ws + QBF_BYTE_OFF);
    unsigned short* wT  = (unsigned short*)((char*)d_ws + WT_BYTE_OFF);
    unsigned short* fT  = (unsigned short*)((char*)d_ws + FEATT_BYTE_OFF);
    float* out          = (float*)d_out;

    prep_all<<<dim3(7190), 256, 0, stream>>>(Wv, Woff, Wattn, Wout, feat0, feat1, feat2,
                                             x, pe, wT, fT, qbf);
    gemm_vq<<<dim3(986), 256, 0, stream>>>(fT, wT, bv, vws, qbf, boff, battn, qraw);
    sample_kernel<<<dim3(BATCH * NQ_ / 2), 384, 0, stream>>>(qraw, coor, c2i, l2c, vws, mid);
    out_gemm<<<dim3(128, 2), 256, 0, stream>>>(mid, wT + WOUTT_OFF, bout, out);
}

// Round 6
// 243.878 us; speedup vs baseline: 2.9664x; 1.0070x over previous
//
#include <hip/hip_runtime.h>
#include <hip/hip_bf16.h>

#define NQ_   8192
#define DM_   256
#define NH_   6
#define DH_   64
#define BATCH 2

typedef __attribute__((ext_vector_type(8))) short short8;
typedef __attribute__((ext_vector_type(4))) short short4v;
typedef __attribute__((ext_vector_type(4))) float float4v;

// ---------------- workspace layout ----------------
static const size_t VOFF_L0 = 0;
static const size_t VOFF_L1 = 5898240;
static const size_t VOFF_L2 = 7372800;
static const size_t QRAW_BYTE_OFF  = 15482880;
static const size_t MID_BYTE_OFF   = 47333376;   // mid bf16 [16384][384]
static const size_t QBF_BYTE_OFF   = 47333376;   // qbf bf16 [16384][256] — aliases mid (lifetimes disjoint)
static const size_t WT_BYTE_OFF    = 59916288;
static const size_t FEATT_BYTE_OFF = 60558336;
// wT element offsets
static const size_t WVT_OFF   = 0;        // 384 rows x 256
static const size_t WOFFT_OFF = 98304;    // 324 rows x 256
static const size_t WOUTT_OFF = 222720;   // 256 rows x 384
// featT element offsets
static const size_t FT_L0 = 0;
static const size_t FT_L1 = 3932160;
static const size_t FT_L2 = 4915200;

__device__ __forceinline__ unsigned short f2bf(float f) {
    unsigned int u = __float_as_uint(f);
    unsigned int r = (u + 0x7fffu + ((u >> 16) & 1u)) >> 16;
    return (unsigned short)r;
}

// ============ prep_all: weights T (0..1125) | feat T (1126..6165) | qbf = bf16(x+pe) (6166..7189) ============
__global__ __launch_bounds__(256) void prep_all(const float* __restrict__ Wv,
                                                const float* __restrict__ Woff,
                                                const float* __restrict__ Wattn,
                                                const float* __restrict__ Wout,
                                                const float* __restrict__ feat0,
                                                const float* __restrict__ feat1,
                                                const float* __restrict__ feat2,
                                                const float* __restrict__ x,
                                                const float* __restrict__ pe,
                                                unsigned short* __restrict__ wT,
                                                unsigned short* __restrict__ fT,
                                                unsigned short* __restrict__ qbf) {
    const int pid = blockIdx.x, t = threadIdx.x;
    if (pid < 1126) {
        int r = pid;
        const float* src; int N, n, K; size_t doff;
        if (r < 384)      { src = Wv;    N = 384; n = r;       K = 256; doff = (size_t)r * 256; }
        else if (r < 708) { src = Woff;  N = 324; n = r - 384; K = 256; doff = (size_t)r * 256; }
        else if (r < 870) { src = Wattn; N = 162; n = r - 708; K = 256; doff = (size_t)r * 256; }
        else              { src = Wout;  N = 256; n = r - 870; K = 384; doff = WOUTT_OFF + (size_t)(r - 870) * 384; }
        for (int k = t; k < K; k += 256) wT[doff + k] = f2bf(src[(size_t)k * N + n]);
        return;
    }
    if (pid < 6166) {
        __shared__ float tile[32][33];
        int f = pid - 1126;
        const float* src; unsigned short* dst; int HW;
        if (f < 3840)      { src = feat0; dst = fT + FT_L0; HW = 7680; }
        else if (f < 4800) { src = feat1; dst = fT + FT_L1; HW = 1920; f -= 3840; }
        else               { src = feat2; dst = fT + FT_L2; HW = 480;  f -= 4800; }
        int pb = f >> 4, rem = f & 15, cb = rem >> 1, b = rem & 1;
        int p0 = pb * 32, c0 = cb * 32;
        int tx = t & 31, ty = t >> 5;
#pragma unroll
        for (int i = 0; i < 4; ++i) {
            int c = c0 + ty + i * 8;
            tile[ty + i * 8][tx] = src[((size_t)(b * DM_ + c)) * HW + p0 + tx];
        }
        __syncthreads();
#pragma unroll
        for (int i = 0; i < 4; ++i) {
            int p = p0 + ty + i * 8;
            dst[((size_t)b * HW + p) * DM_ + c0 + tx] = f2bf(tile[tx][ty + i * 8]);
        }
        return;
    }
    // qbf: 1024 blocks, 4096 elements each
    int f = pid - 6166;
#pragma unroll
    for (int i = 0; i < 4; ++i) {
        size_t e = (size_t)f * 4096 + i * 1024 + t * 4;
        float4 xv = *(const float4*)&x[e];
        float4 pv = *(const float4*)&pe[e];
        short4v o;
        o[0] = (short)f2bf(xv.x + pv.x);
        o[1] = (short)f2bf(xv.y + pv.y);
        o[2] = (short)f2bf(xv.z + pv.z);
        o[3] = (short)f2bf(xv.w + pv.w);
        *(short4v*)&qbf[e] = o;
    }
}

// ============ shared MFMA inner block: 128x128 tile, 4 waves 2x2, 4x4 frags ============
__device__ __forceinline__ void mfma_block(const short A[][40], const short B[][40],
                                           int wm, int wn, int lane, float4v acc[4][4]) {
    int m_base = wm + (lane & 15);
    int n_base = wn + (lane & 15);
    int q8 = (lane >> 4) * 8;
    short8 af[4], bf[4];
#pragma unroll
    for (int i = 0; i < 4; ++i) af[i] = *(const short8*)&A[m_base + i * 16][q8];
#pragma unroll
    for (int j = 0; j < 4; ++j) bf[j] = *(const short8*)&B[n_base + j * 16][q8];
#pragma unroll
    for (int i = 0; i < 4; ++i)
#pragma unroll
        for (int j = 0; j < 4; ++j)
            acc[i][j] = __builtin_amdgcn_mfma_f32_16x16x32_bf16(af[i], bf[j], acc[i][j], 0, 0, 0);
}

// ============ fused value GEMM (blocks 0..473) + query GEMM (blocks 474..985) ============
__global__ __launch_bounds__(256) void gemm_vq(const unsigned short* __restrict__ fT,
                                               const unsigned short* __restrict__ wT,
                                               const float* __restrict__ bv,
                                               unsigned short* __restrict__ vws,
                                               const unsigned short* __restrict__ qbf,
                                               const float* __restrict__ boff,
                                               const float* __restrict__ battn,
                                               float* __restrict__ qraw) {
    __shared__ short A[128][40];
    __shared__ short B[128][40];
    const int tid = threadIdx.x;
    const int lane = tid & 63, wave = tid >> 6;
    const int wm = (wave & 1) * 64, wn = (wave >> 1) * 64;
    const int id = blockIdx.x;
    float4v acc[4][4];
#pragma unroll
    for (int i = 0; i < 4; ++i)
#pragma unroll
        for (int j = 0; j < 4; ++j) acc[i][j] = (float4v){0.f, 0.f, 0.f, 0.f};

    if (id < 474) {
        // ---- value path ----
        int pb = id / 6, rem = id % 6;
        int nb = rem >> 1, b = rem & 1;
        int pbl, HW; size_t ftoff, voff;
        if (pb < 60)      { pbl = pb;      HW = 7680; ftoff = FT_L0; voff = VOFF_L0; }
        else if (pb < 75) { pbl = pb - 60; HW = 1920; ftoff = FT_L1; voff = VOFF_L1; }
        else              { pbl = pb - 75; HW = 480;  ftoff = FT_L2; voff = VOFF_L2; }
        const int p0 = pbl * 128, n0 = nb * 128;
        const unsigned short* Asrc = fT + ftoff + (size_t)b * HW * DM_;
        const unsigned short* wvT = wT + WVT_OFF;

        for (int k0 = 0; k0 < DM_; k0 += 32) {
#pragma unroll
            for (int it = 0; it < 2; ++it) {
                int idx = tid + it * 256;
                int r = idx >> 2, sg = idx & 3;
                int p = p0 + r; if (p >= HW) p = HW - 1;
                *(short8*)&A[r][sg * 8] = *(const short8*)&Asrc[(size_t)p * DM_ + k0 + sg * 8];
                *(short8*)&B[r][sg * 8] = *(const short8*)&wvT[(size_t)(n0 + r) * DM_ + k0 + sg * 8];
            }
            __syncthreads();
            mfma_block(A, B, wm, wn, lane, acc);
            __syncthreads();
        }
        int colb = n0 + wn + (lane & 15);
        int rowq = (lane >> 4) * 4;
#pragma unroll
        for (int i = 0; i < 4; ++i)
#pragma unroll
            for (int j = 0; j < 4; ++j) {
                int n = colb + j * 16;
                int h = n >> 6, d = n & 63;
                float bias = bv[n];
#pragma unroll
                for (int r = 0; r < 4; ++r) {
                    int p = p0 + wm + i * 16 + rowq + r;
                    if (p < HW)
                        vws[voff + ((size_t)(b * NH_ + h) * HW + p) * DH_ + d] = f2bf(acc[i][j][r] + bias);
                }
            }
    } else {
        // ---- query path (bf16 staging from qbf) ----
        int qid = id - 474;
        const int m0 = (qid & 127) * 128, n0 = (qid >> 7) * 128;
        for (int k0 = 0; k0 < DM_; k0 += 32) {
#pragma unroll
            for (int it = 0; it < 2; ++it) {
                int idx = tid + it * 256;
                int r = idx >> 2, sg = idx & 3;
                *(short8*)&A[r][sg * 8] = *(const short8*)&qbf[(size_t)(m0 + r) * DM_ + k0 + sg * 8];
                int g = n0 + r;
                short8 bz = (short8)0;
                if (g < 486) bz = *(const short8*)&wT[WOFFT_OFF + (size_t)g * DM_ + k0 + sg * 8];
                *(short8*)&B[r][sg * 8] = bz;
            }
            __syncthreads();
            mfma_block(A, B, wm, wn, lane, acc);
            __syncthreads();
        }
        int colb = n0 + wn + (lane & 15);
        int rowq = (lane >> 4) * 4;
#pragma unroll
        for (int i = 0; i < 4; ++i)
#pragma unroll
            for (int j = 0; j < 4; ++j) {
                int n = colb + j * 16;
                if (n < 486) {
                    float bias = (n < 324) ? boff[n] : battn[n - 324];
#pragma unroll
                    for (int r = 0; r < 4; ++r) {
                        int m = m0 + wm + i * 16 + rowq + r;
                        qraw[(size_t)m * 486 + n] = acc[i][j][r] + bias;
                    }
                }
            }
    }
}

// ============ fused softmax + projection + gather, 2 queries per block ============
// plan LDS: s_plan[q][corner][170]; corner = (y<<1)|x; entry = {abs_byte_off(y,x baked), w bits}
// gather: wave h = head h; lane>>4 = corner; lane&15 = channel quad (8B bf16)
__global__ __launch_bounds__(384) void sample_kernel(const float* __restrict__ qraw,
                                                     const float* __restrict__ coor,
                                                     const float* __restrict__ cam2img,
                                                     const float* __restrict__ l2c,
                                                     const unsigned short* __restrict__ vws,
                                                     unsigned short* __restrict__ mid) {
    __shared__ int2 s_plan[2][4][170];
    const int tid = threadIdx.x;
    const int bq0 = blockIdx.x * 2;

    {
        int q = tid >= 192;
        int t = tid - q * 192;
        int bq = bq0 + q;
        int b = bq >> 13;
        int h = t >> 5, j = t & 31;
        bool act = j < 27;
        float logit = act ? qraw[(size_t)bq * 486 + 324 + h * 27 + j] : -1e30f;
        float m = logit;
#pragma unroll
        for (int msk = 16; msk >= 1; msk >>= 1) m = fmaxf(m, __shfl_xor(m, msk, 32));
        float e = act ? __expf(logit - m) : 0.f;
        float ssum = e;
#pragma unroll
        for (int msk = 16; msk >= 1; msk >>= 1) ssum += __shfl_xor(ssum, msk, 32);
        if (act) {
            float attn = e * __frcp_rn(ssum);
            int l = (j >= 18) ? 2 : ((j >= 9) ? 1 : 0);
            int wl = 160 >> l, hl = 48 >> l;
            int HWl = (l == 0) ? 7680 : ((l == 1) ? 1920 : 480);
            int lvlb = (l == 0) ? 0 : ((l == 1) ? 11796480 : 14745600);
            float sc = (l == 0) ? 0.125f : ((l == 1) ? 0.0625f : 0.03125f);
            float c0 = coor[(size_t)bq * 3 + 0];
            float c1 = coor[(size_t)bq * 3 + 1];
            float c2 = coor[(size_t)bq * 3 + 2];
            const float* L = l2c + b * 16;
            const float* C = cam2img + b * 16;
            float pc0 = L[0] * c0 + L[1] * c1 + L[2]  * c2 + L[3];
            float pc1 = L[4] * c0 + L[5] * c1 + L[6]  * c2 + L[7];
            float pc2 = L[8] * c0 + L[9] * c1 + L[10] * c2 + L[11];
            float q0 = C[0] * pc0 + C[1] * pc1 + C[2]  * pc2 + C[3];
            float q1 = C[4] * pc0 + C[5] * pc1 + C[6]  * pc2 + C[7];
            float q2 = C[8] * pc0 + C[9] * pc1 + C[10] * pc2 + C[11];
            float rz = __frcp_rn(q2);
            float refx = q0 * rz * sc, refy = q1 * rz * sc;
            float2 oxy = *(const float2*)&qraw[(size_t)bq * 486 + h * 54 + j * 2];
            float X = refx + oxy.x - 0.5f;
            float Y = refy + oxy.y - 0.5f;
            float x0f = floorf(X), y0f = floorf(Y);
            float fx = X - x0f, fy = Y - y0f;
            int ix = (int)x0f, iy = (int)y0f;
            int bx = min(max(ix, 0), wl - 2);
            float wx0 = ((bx == ix) ? (1.f - fx) : 0.f) + ((bx == ix + 1) ? fx : 0.f);
            float wx1 = ((bx + 1 == ix) ? (1.f - fx) : 0.f) + ((bx + 1 == ix + 1) ? fx : 0.f);
            int cy0 = min(max(iy, 0), hl - 1);
            int cy1 = min(max(iy + 1, 0), hl - 1);
            float wy0 = (iy >= 0 && iy < hl) ? (1.f - fy) : 0.f;
            float wy1 = (iy + 1 >= 0 && iy + 1 < hl) ? fy : 0.f;
            int jj = h * 27 + j;
            int slice = (b * NH_ + h) * HWl;
            int off0 = lvlb + (slice + cy0 * wl + bx) * 128;
            int off1 = lvlb + (slice + cy1 * wl + bx) * 128;
            s_plan[q][0][jj] = make_int2(off0,       __float_as_int(attn * wy0 * wx0));
            s_plan[q][1][jj] = make_int2(off0 + 128, __float_as_int(attn * wy0 * wx1));
            s_plan[q][2][jj] = make_int2(off1,       __float_as_int(attn * wy1 * wx0));
            s_plan[q][3][jj] = make_int2(off1 + 128, __float_as_int(attn * wy1 * wx1));
        }
    }
    __syncthreads();

    const int h = tid >> 6;
    const int lane = tid & 63;
    const int sel = lane >> 4;                      // corner
    const unsigned lb = (unsigned)((lane & 15) << 3);  // channel-quad byte offset within pixel
    const char* vbase = (const char*)vws;
    const int2* p0 = &s_plan[0][sel][h * 27];
    const int2* p1 = &s_plan[1][sel][h * 27];
    float b0 = 0.f, b1 = 0.f, b2 = 0.f, b3 = 0.f;
    float c0 = 0.f, c1 = 0.f, c2 = 0.f, c3 = 0.f;
#pragma unroll
    for (int g = 0; g < 3; ++g) {
        int2 ow0[9], ow1[9];
        uint2 d0[9], d1[9];
#pragma unroll
        for (int t = 0; t < 9; ++t) {
            ow0[t] = p0[g * 9 + t];
            ow1[t] = p1[g * 9 + t];
        }
#pragma unroll
        for (int t = 0; t < 9; ++t) {
            d0[t] = *(const uint2*)(vbase + ((unsigned)ow0[t].x + lb));
            d1[t] = *(const uint2*)(vbase + ((unsigned)ow1[t].x + lb));
        }
#pragma unroll
        for (int t = 0; t < 9; ++t) {
            float w0 = __int_as_float(ow0[t].y);
            float w1 = __int_as_float(ow1[t].y);
            b0 = fmaf(w0, __uint_as_float(d0[t].x << 16), b0);
            b1 = fmaf(w0, __uint_as_float(d0[t].x & 0xffff0000u), b1);
            b2 = fmaf(w0, __uint_as_float(d0[t].y << 16), b2);
            b3 = fmaf(w0, __uint_as_float(d0[t].y & 0xffff0000u), b3);
            c0 = fmaf(w1, __uint_as_float(d1[t].x << 16), c0);
            c1 = fmaf(w1, __uint_as_float(d1[t].x & 0xffff0000u), c1);
            c2 = fmaf(w1, __uint_as_float(d1[t].y << 16), c2);
            c3 = fmaf(w1, __uint_as_float(d1[t].y & 0xffff0000u), c3);
        }
    }
    b0 += __shfl_xor(b0, 16, 64);  c0 += __shfl_xor(c0, 16, 64);
    b1 += __shfl_xor(b1, 16, 64);  c1 += __shfl_xor(c1, 16, 64);
    b2 += __shfl_xor(b2, 16, 64);  c2 += __shfl_xor(c2, 16, 64);
    b3 += __shfl_xor(b3, 16, 64);  c3 += __shfl_xor(c3, 16, 64);
    b0 += __shfl_xor(b0, 32, 64);  c0 += __shfl_xor(c0, 32, 64);
    b1 += __shfl_xor(b1, 32, 64);  c1 += __shfl_xor(c1, 32, 64);
    b2 += __shfl_xor(b2, 32, 64);  c2 += __shfl_xor(c2, 32, 64);
    b3 += __shfl_xor(b3, 32, 64);  c3 += __shfl_xor(c3, 32, 64);
    if (lane < 16) {
        uint2 pk0, pk1;
        pk0.x = (unsigned)f2bf(b0) | ((unsigned)f2bf(b1) << 16);
        pk0.y = (unsigned)f2bf(b2) | ((unsigned)f2bf(b3) << 16);
        pk1.x = (unsigned)f2bf(c0) | ((unsigned)f2bf(c1) << 16);
        pk1.y = (unsigned)f2bf(c2) | ((unsigned)f2bf(c3) << 16);
        *(uint2*)&mid[(size_t)bq0 * 384 + h * DH_ + (lane << 2)] = pk0;
        *(uint2*)&mid[(size_t)(bq0 + 1) * 384 + h * DH_ + (lane << 2)] = pk1;
    }
}

// ============ out GEMM: 64x128 tiles (512 blocks, 2/CU) ============
__global__ __launch_bounds__(256) void out_gemm(const unsigned short* __restrict__ mid,
                                                const unsigned short* __restrict__ woT,
                                                const float* __restrict__ bout,
                                                float* __restrict__ out) {
    __shared__ short A[64][40];
    __shared__ short B[128][40];
    const int tid = threadIdx.x;
    const int m0 = blockIdx.x * 64, n0 = blockIdx.y * 128;
    const int lane = tid & 63, wave = tid >> 6;
    const int wn = wave * 32;
    float4v acc[4][2];
#pragma unroll
    for (int i = 0; i < 4; ++i)
#pragma unroll
        for (int j = 0; j < 2; ++j) acc[i][j] = (float4v){0.f, 0.f, 0.f, 0.f};

    for (int k0 = 0; k0 < 384; k0 += 32) {
        {
            int r = tid >> 2, sg = tid & 3;
            *(short8*)&A[r][sg * 8] = *(const short8*)&mid[(size_t)(m0 + r) * 384 + k0 + sg * 8];
        }
#pragma unroll
        for (int it = 0; it < 2; ++it) {
            int idx = tid + it * 256;
            int r = idx >> 2, sg = idx & 3;
            *(short8*)&B[r][sg * 8] = *(const short8*)&woT[(size_t)(n0 + r) * 384 + k0 + sg * 8];
        }
        __syncthreads();
        {
            int m_base = lane & 15;
            int n_base = wn + (lane & 15);
            int q8 = (lane >> 4) * 8;
            short8 af[4], bf[2];
#pragma unroll
            for (int i = 0; i < 4; ++i) af[i] = *(const short8*)&A[m_base + i * 16][q8];
#pragma unroll
            for (int j = 0; j < 2; ++j) bf[j] = *(const short8*)&B[n_base + j * 16][q8];
#pragma unroll
            for (int i = 0; i < 4; ++i)
#pragma unroll
                for (int j = 0; j < 2; ++j)
                    acc[i][j] = __builtin_amdgcn_mfma_f32_16x16x32_bf16(af[i], bf[j], acc[i][j], 0, 0, 0);
        }
        __syncthreads();
    }
    int colb = n0 + wn + (lane & 15);
    int rowq = (lane >> 4) * 4;
#pragma unroll
    for (int i = 0; i < 4; ++i)
#pragma unroll
        for (int j = 0; j < 2; ++j) {
            int n = colb + j * 16;
            float bias = bout[n];
#pragma unroll
            for (int r = 0; r < 4; ++r) {
                int m = m0 + i * 16 + rowq + r;
                out[(size_t)m * 256 + n] = acc[i][j][r] + bias;
            }
        }
}

extern "C" void kernel_launch(void* const* d_in, const int* in_sizes, int n_in,
                              void* d_out, int out_size, void* d_ws, size_t ws_size,
                              hipStream_t stream) {
    const float* x      = (const float*)d_in[0];
    const float* pe     = (const float*)d_in[1];
    const float* coor   = (const float*)d_in[2];
    const float* c2i    = (const float*)d_in[3];
    const float* l2c    = (const float*)d_in[4];
    const float* feat0  = (const float*)d_in[5];
    const float* feat1  = (const float*)d_in[6];
    const float* feat2  = (const float*)d_in[7];
    const float* Wv     = (const float*)d_in[8];
    const float* bv     = (const float*)d_in[9];
    const float* Woff   = (const float*)d_in[10];
    const float* boff   = (const float*)d_in[11];
    const float* Wattn  = (const float*)d_in[12];
    const float* battn  = (const float*)d_in[13];
    const float* Wout   = (const float*)d_in[14];
    const float* bout   = (const float*)d_in[15];

    unsigned short* vws = (unsigned short*)d_ws;
    float* qraw         = (float*)((char*)d_ws + QRAW_BYTE_OFF);
    unsigned short* mid = (unsigned short*)((char*)d_ws + MID_BYTE_OFF);
    unsigned short* qbf = (unsigned short*)((char*)d_ws + QBF_BYTE_OFF);
    unsigned short* wT  = (unsigned short*)((char*)d_ws + WT_BYTE_OFF);
    unsigned short* fT  = (unsigned short*)((char*)d_ws + FEATT_BYTE_OFF);
    float* out          = (float*)d_out;

    prep_all<<<dim3(7190), 256, 0, stream>>>(Wv, Woff, Wattn, Wout, feat0, feat1, feat2,
                                             x, pe, wT, fT, qbf);
    gemm_vq<<<dim3(986), 256, 0, stream>>>(fT, wT, bv, vws, qbf, boff, battn, qraw);
    sample_kernel<<<dim3(BATCH * NQ_ / 2), 384, 0, stream>>>(qraw, coor, c2i, l2c, vws, mid);
    out_gemm<<<dim3(256, 2), 256, 0, stream>>>(mid, wT + WOUTT_OFF, bout, out);
}